// Round 10
// baseline (2967.862 us; speedup 1.0000x reference)
//
#include <hip/hip_runtime.h>
#include <hip/hip_bf16.h>

// CirculantElmanCell: T=1024, B=16, D=2048
// out0: output [T,B,D] f32 ; out1: h [T+1,B,D] f32 (concatenated in d_out)

typedef __attribute__((ext_vector_type(8))) unsigned short us8;
typedef __attribute__((ext_vector_type(8))) __bf16 bf16x8;
typedef __attribute__((ext_vector_type(4))) float f32x4;
typedef __attribute__((ext_vector_type(4))) unsigned int u32x4;

__device__ __forceinline__ int SIGF(int a){ return a ^ (((a >> 8) & 3) << 2) ^ ((a >> 6) & 3); }
__device__ __forceinline__ int rev2i(int v){ return ((v & 1) << 1) | ((v >> 1) & 1); }
// DIF digit permutation; involution (digits reversed + per-digit bitrev)
__device__ __forceinline__ int PERMF(int i){
  return rev2i((i >> 8) & 3) | (rev2i((i >> 6) & 3) << 2) | (rev2i((i >> 4) & 3) << 4)
       | (rev2i((i >> 2) & 3) << 6) | (rev2i(i & 3) << 8);
}

// LDS-only barrier: no vmcnt drain
#define LDSBAR() do { \
  asm volatile("s_waitcnt lgkmcnt(0)\n\ts_barrier" ::: "memory"); \
  __builtin_amdgcn_sched_barrier(0); \
} while (0)
// full barrier: drains vmem too (hazard fence for cross-thread load->store)
#define FULLBAR() do { \
  asm volatile("s_waitcnt vmcnt(0) lgkmcnt(0)\n\ts_barrier" ::: "memory"); \
  __builtin_amdgcn_sched_barrier(0); \
} while (0)

__device__ __forceinline__ void sincos2pi(float fr, float& sn, float& co){
#if __has_builtin(__builtin_amdgcn_sinf) && __has_builtin(__builtin_amdgcn_cosf)
  sn = __builtin_amdgcn_sinf(fr);   // v_sin_f32: revolutions
  co = __builtin_amdgcn_cosf(fr);
#else
  __sincosf(fr * 6.28318530717958647692f, &sn, &co);
#endif
}

__device__ __forceinline__ float2 cmul(float2 a, float2 b){
  return make_float2(a.x*b.x - a.y*b.y, a.x*b.y + a.y*b.x);
}
__device__ __forceinline__ float2 cmulc(float2 a, float2 b){   // a * conj(b)
  return make_float2(a.x*b.x + a.y*b.y, a.y*b.x - a.x*b.y);
}
__device__ __forceinline__ float2 cadd(float2 a, float2 b){ return make_float2(a.x+b.x, a.y+b.y); }
__device__ __forceinline__ float2 csub(float2 a, float2 b){ return make_float2(a.x-b.x, a.y-b.y); }

__device__ __forceinline__ float tanh_fast(float x){
  float e = __expf(2.0f * x);
  return 1.0f - 2.0f / (e + 1.0f);
}

__device__ __forceinline__ float2 wn(int num, float dinv, int sgn){
  float sn, co; sincos2pi((float)num * dinv, sn, co);
  return make_float2(co, sgn > 0 ? sn : -sn);
}

// packed f32x2 -> bf16x2 (RNE), low16 = lo
__device__ __forceinline__ unsigned int cvtpk(float lo, float hi){
  unsigned int r;
  asm("v_cvt_pk_bf16_f32 %0, %1, %2" : "=v"(r) : "v"(lo), "v"(hi));
  return r;
}

// ---------------- cross-lane exchange primitives ----------------
template<int CTRL>
__device__ __forceinline__ float2 dpp2(float2 v){
  float2 r;
  r.x = __int_as_float(__builtin_amdgcn_mov_dpp(__float_as_int(v.x), CTRL, 0xF, 0xF, true));
  r.y = __int_as_float(__builtin_amdgcn_mov_dpp(__float_as_int(v.y), CTRL, 0xF, 0xF, true));
  return r;
}
template<int IMM>
__device__ __forceinline__ float2 swz2(float2 v){
  float2 r;
  r.x = __int_as_float(__builtin_amdgcn_ds_swizzle(__float_as_int(v.x), IMM));
  r.y = __int_as_float(__builtin_amdgcn_ds_swizzle(__float_as_int(v.y), IMM));
  return r;
}
__device__ __forceinline__ float2 bperm2(int addr, float2 v){
  float2 r;
  r.x = __int_as_float(__builtin_amdgcn_ds_bpermute(addr, __float_as_int(v.x)));
  r.y = __int_as_float(__builtin_amdgcn_ds_bpermute(addr, __float_as_int(v.y)));
  return r;
}
#define DPP_XOR1 0xB1  // quad_perm [1,0,3,2]
#define DPP_XOR2 0x4E  // quad_perm [2,3,0,1]

// ---------------- folded butterfly core (verified R8/R9) ----------------
template<int CONJ>
__device__ __forceinline__ float2 fold2(float2 u, float2 v, float2 C1, float2 C2){
  float2 r;
  if (!CONJ){
    r.x = u.x*C1.x - u.y*C1.y + v.x*C2.x - v.y*C2.y;
    r.y = u.x*C1.y + u.y*C1.x + v.x*C2.y + v.y*C2.x;
  } else {
    r.x = u.x*C1.x + u.y*C1.y + v.x*C2.x + v.y*C2.y;
    r.y = u.y*C1.x - u.x*C1.y + v.y*C2.x - v.x*C2.y;
  }
  return r;
}

template<int POS>
__device__ __forceinline__ float2 lds4f(const float2* buf, int a0, int a1, int a2, int a3,
                                        float sB, float2 C1, float2 C2){
  float2 in0 = buf[a0], in1 = buf[a1], in2 = buf[a2], in3 = buf[a3];
  float2 u = make_float2(fmaf(sB, in2.x, in0.x), fmaf(sB, in2.y, in0.y));
  float2 v = make_float2(fmaf(sB, in3.x, in1.x), fmaf(sB, in3.y, in1.y));
  return fold2<POS>(u, v, C1, C2);
}

template<int POS>
__device__ __forceinline__ float2 lanes3f(float2 T, int bpa,
    float sH2, float2 E1, float2 E2,
    float sH3, float2 F1, float2 F2,
    float sH4, float2 G1, float2 G2){
  { float2 par = bperm2(bpa, T);
    T.x = fmaf(sH2, T.x, par.x); T.y = fmaf(sH2, T.y, par.y);
    float2 p2 = swz2<0x401F>(T);
    T = fold2<POS>(T, p2, E1, E2); }
  { float2 par = swz2<0x201F>(T);
    T.x = fmaf(sH3, T.x, par.x); T.y = fmaf(sH3, T.y, par.y);
    float2 p2 = swz2<0x101F>(T);
    T = fold2<POS>(T, p2, F1, F2); }
  { float2 par = dpp2<DPP_XOR2>(T);
    T.x = fmaf(sH4, T.x, par.x); T.y = fmaf(sH4, T.y, par.y);
    float2 p2 = dpp2<DPP_XOR1>(T);
    T = fold2<POS>(T, p2, G1, G2); }
  return T;
}

// ---------------- per-thread constants ----------------
struct TW {
  float2 A1, A2, B1, B2;
  float2 E1, E2, F1, F2, G1, G2;
  float2 wmd;
  float sB0, sB1, sH2, sH3, sH4;
  int sfi, swP, smir, bpa, pb;
  int aA0, aA1, aA2, aA3, aB0, aB1, aB2, aB3;
};

__device__ __forceinline__ float2 scal(float2 a, float s){ return make_float2(a.x*s, a.y*s); }

__device__ __forceinline__ void make_tw(int i, TW& S){
  const int p0 = rev2i((i >> 8) & 3);
  const int p1 = rev2i((i >> 6) & 3);
  const int p2v = rev2i((i >> 4) & 3);
  const int p3v = rev2i((i >> 2) & 3);
  const float2 tw0 = wn(((i & 255) * p0) & 1023, 1.0f/1024.0f, -1);
  const float2 tw1 = wn(((i & 63) * p1) & 255, 1.0f/256.0f, -1);
  const float2 tw2 = wn(((i & 15) * p2v) & 63, 1.0f/64.0f, -1);
  const float2 tw3 = wn(((i & 3) * p3v) & 15, 1.0f/16.0f, -1);
  S.wmd = wn(i & 2047, 1.0f/2048.0f, -1);
  const float sD0 = (p0 & 2) ? -1.f : 1.f;  const bool sel0 = p0 & 1;
  const float sD1 = (p1 & 2) ? -1.f : 1.f;  const bool sel1 = p1 & 1;
  S.sB0 = (p0 & 1) ? -1.f : 1.f;
  S.sB1 = (p1 & 1) ? -1.f : 1.f;
  const float2 rho0 = sel0 ? make_float2(0.f,-1.f) : make_float2(1.f,0.f);
  const float2 rho1 = sel1 ? make_float2(0.f,-1.f) : make_float2(1.f,0.f);
  S.A1 = tw0; S.A2 = scal(cmul(tw0, rho0), sD0);
  S.B1 = tw1; S.B2 = scal(cmul(tw1, rho1), sD1);
  const bool c02 = (i >> 4) & 1, c12 = (i >> 5) & 1;
  const bool c03 = (i >> 2) & 1, c13 = (i >> 3) & 1;
  const bool c04 = i & 1,        c14 = (i >> 1) & 1;
  S.sH2 = c12 ? -1.f : 1.f;
  S.sH3 = c13 ? -1.f : 1.f;
  S.sH4 = c14 ? -1.f : 1.f;
  {
    const float sL = c02 ? -1.f : 1.f;
    const float2 rho = c12 ? make_float2(0.f,-1.f) : make_float2(1.f,0.f);
    const float2 al = c02 ? scal(rho, sL) : make_float2(1.f,0.f);
    const float2 be = c02 ? make_float2(1.f,0.f) : scal(rho, sL);
    S.E1 = cmul(tw2, al); S.E2 = cmul(tw2, be);
  }
  {
    const float sL = c03 ? -1.f : 1.f;
    const float2 rho = c13 ? make_float2(0.f,-1.f) : make_float2(1.f,0.f);
    const float2 al = c03 ? scal(rho, sL) : make_float2(1.f,0.f);
    const float2 be = c03 ? make_float2(1.f,0.f) : scal(rho, sL);
    S.F1 = cmul(tw3, al); S.F2 = cmul(tw3, be);
  }
  {
    const float sL = c04 ? -1.f : 1.f;
    const float2 rho = c14 ? make_float2(0.f,-1.f) : make_float2(1.f,0.f);
    S.G1 = c04 ? scal(rho, sL) : make_float2(1.f,0.f);
    S.G2 = c04 ? make_float2(1.f,0.f) : scal(rho, sL);
  }
  S.sfi = SIGF(i); S.swP = SIGF(PERMF(i)); S.smir = SIGF((1024 - i) & 1023);
  S.pb = PERMF(i);
  S.bpa = ((i & 63) ^ 32) << 2;
  const int r256 = i & 255;
  S.aA0 = SIGF(r256); S.aA1 = SIGF(r256 + 256); S.aA2 = SIGF(r256 + 512); S.aA3 = SIGF(r256 + 768);
  const int b64 = (i & ~255) + (i & 63);
  S.aB0 = SIGF(b64); S.aB1 = SIGF(b64 + 64); S.aB2 = SIGF(b64 + 128); S.aB3 = SIGF(b64 + 192);
}

// conv body: returns y @ position PERM(i) (the P5 register value).
// P2's barrier is a FULL drain: all threads' earlier global loads complete
// before any thread's later stores (cross-thread hazard fence).
__device__ __forceinline__ float2 fftconv(float2* hz, float2* bA, float2* bB,
                                          const TW& S, float2 P, float2 Q){
  float2 T = lds4f<0>(hz, S.aA0, S.aA1, S.aA2, S.aA3, S.sB0, S.A1, S.A2);
  bA[S.sfi] = T; LDSBAR();
  T = lds4f<0>(bA, S.aB0, S.aB1, S.aB2, S.aB3, S.sB1, S.B1, S.B2);
  T = lanes3f<0>(T, S.bpa, S.sH2, S.E1, S.E2, S.sH3, S.F1, S.F2, S.sH4, S.G1, S.G2);
  bB[S.swP] = T; FULLBAR();
  {
    float2 zk = bB[S.sfi], zp = bB[S.smir];
    bA[S.sfi] = cadd(cmul(P, zk), cmulc(Q, zp));
  }
  LDSBAR();
  T = lds4f<1>(bA, S.aA0, S.aA1, S.aA2, S.aA3, S.sB0, S.A1, S.A2);
  bB[S.sfi] = T; LDSBAR();
  T = lds4f<1>(bB, S.aB0, S.aB1, S.aB2, S.aB3, S.sB1, S.B1, S.B2);
  T = lanes3f<1>(T, S.bpa, S.sH2, S.E1, S.E2, S.sH3, S.F1, S.F2, S.sH4, S.G1, S.G2);
  return T;   // y @ PERM(i); caller writes epilogue + trailing barrier
}

// in-block lam + P/Q from real 2048-seq c (verified R9)
__device__ __forceinline__ void make_PQ(const float* __restrict__ c, int i, const TW& S,
                                        float2* hz, float2* bA, float2* bB,
                                        float2& P, float2& Q){
  hz[S.sfi] = ((const float2*)c)[i];
  __syncthreads();
  float2 T = lds4f<0>(hz, S.aA0, S.aA1, S.aA2, S.aA3, S.sB0, S.A1, S.A2);
  bA[S.sfi] = T;
  __syncthreads();
  T = lds4f<0>(bA, S.aB0, S.aB1, S.aB2, S.aB3, S.sB1, S.B1, S.B2);
  T = lanes3f<0>(T, S.bpa, S.sH2, S.E1, S.E2, S.sH3, S.F1, S.F2, S.sH4, S.G1, S.G2);
  bB[S.swP] = T;
  __syncthreads();
  float2 zk = bB[S.sfi], zp = bB[S.smir];
  float2 E = make_float2(0.5f*(zk.x+zp.x),  0.5f*(zk.y-zp.y));
  float2 O = make_float2(0.5f*(zk.y+zp.y), -0.5f*(zk.x-zp.x));
  float2 w = S.wmd;
  float2 wO = cmul(w, O);
  float2 lamA = scal(cadd(E, wO), 1.0f/2048.0f);
  float2 lamB = scal(csub(E, wO), 1.0f/2048.0f);
  float2 al = make_float2(0.5f*(1.0f + w.y), -0.5f*w.x);
  float2 be = make_float2(0.5f*(1.0f - w.y),  0.5f*w.x);
  float2 ga = make_float2(1.0f + w.y,  w.x);
  float2 de = make_float2(1.0f - w.y, -w.x);
  float2 gA = cmul(ga, lamA), dB = cmul(de, lamB);
  P = cadd(cmul(gA, al), cmul(dB, be));
  Q = cadd(cmul(gA, be), cmul(dB, al));
  __syncthreads();
}

// =====================================================================
// mega v5: perm-layout intermediates + K-split gemm.
// blocks [0,16) recur ; [16,144) circx ; [144,4240) gemm (1 tile each).
// pre/gate stored PERMUTED: slot j holds value @ PERM(j). Consumer fuses
// the epilogue into P5 (loads slot i coalesced, stores h/out @ PERM(i)).
// =====================================================================
__global__ __launch_bounds__(1024, 4) void mega(
    const float* __restrict__ x, const float* __restrict__ Wg,
    const float* __restrict__ h0, const float* __restrict__ ch,
    const float* __restrict__ cx, const float* __restrict__ bias,
    const float* __restrict__ bg,
    float* __restrict__ outp, float* __restrict__ houtp, int* __restrict__ flags){
  __shared__ __align__(16) char smem[98304];   // 96KB: 1 block/CU
  const int bid = blockIdx.x;
  const int tid = threadIdx.x;
  int* gcnt = flags;
  int* wcnt = flags + 128;

  if (bid < 16){
    // ---------------- recur consumer (dedicated CU) ----------------
    float2* hz = (float2*)smem; float2* bA = hz + 1024; float2* bB = hz + 2048;
    const int i = tid, b = bid;
    TW S; make_tw(i, S);
    float2 P, Q; make_PQ(ch, i, S, hz, bA, bB, P, Q);
    {
      const float2* h02 = (const float2*)(h0 + (size_t)b * 2048);
      float2* hrow0 = (float2*)(houtp + (size_t)b * 2048);
      float2 v = h02[i]; hz[S.sfi] = v; hrow0[i] = v;
    }
    __syncthreads();
    #pragma unroll 1
    for (int t = 0; t < 1024; ++t){
      if ((t & 7) == 0){
        if (tid == 0){
          const int xk = t >> 3;
          while (__hip_atomic_load(&gcnt[xk], __ATOMIC_RELAXED, __HIP_MEMORY_SCOPE_SYSTEM) < 32)
            __builtin_amdgcn_s_sleep(16);
          while (__hip_atomic_load(&wcnt[xk], __ATOMIC_RELAXED, __HIP_MEMORY_SCOPE_SYSTEM) < 128)
            __builtin_amdgcn_s_sleep(16);
        }
        __syncthreads();
      }
      float* orow = outp  + ((size_t)t * 16 + b) * 2048;
      float* hrow = houtp + ((size_t)(t + 1) * 16 + b) * 2048;
      // coalesced sc1 loads of perm-layout pre/gate: slot i = value @ PERM(i)
      float2 pr, gv;
      pr.x = __hip_atomic_load(orow + 2*i,     __ATOMIC_RELAXED, __HIP_MEMORY_SCOPE_SYSTEM);
      pr.y = __hip_atomic_load(orow + 2*i + 1, __ATOMIC_RELAXED, __HIP_MEMORY_SCOPE_SYSTEM);
      gv.x = __hip_atomic_load(hrow + 2*i,     __ATOMIC_RELAXED, __HIP_MEMORY_SCOPE_SYSTEM);
      gv.y = __hip_atomic_load(hrow + 2*i + 1, __ATOMIC_RELAXED, __HIP_MEMORY_SCOPE_SYSTEM);
      float2 y = fftconv(hz, bA, bB, S, P, Q);   // y @ PERM(i); FULLBAR inside fences loads
      float hx = tanh_fast(y.x + pr.x);
      float hy = tanh_fast(y.y + pr.y);
      float2 hv = make_float2(hx, hy);
      hz[S.swP] = hv;                             // LDS @ PERM(i) -> next P1 reads linear
      ((float2*)hrow)[S.pb] = hv;                 // h @ PERM(i), plain store (no reader)
      ((float2*)orow)[S.pb] = make_float2(hx * gv.x, hy * gv.y);
      LDSBAR();
    }
  } else if (bid < 144){
    // ---------------- circx producer: rows cblk + 128*k, perm-layout out ----------------
    float2* hz = (float2*)smem; float2* bA = hz + 1024; float2* bB = hz + 2048;
    const int i = tid, cblk = bid - 16;
    TW S; make_tw(i, S);
    float2 P, Q; make_PQ(cx, i, S, hz, bA, bB, P, Q);
    const float2 bv = ((const float2*)bias)[S.pb];   // bias @ PERM(i)
    #pragma unroll 1
    for (int k = 0; k < 128; ++k){
      const size_t row = (size_t)cblk + ((size_t)k << 7);
      hz[S.sfi] = ((const float2*)(x + row * 2048))[i];
      LDSBAR();
      float2 y = fftconv(hz, bA, bB, S, P, Q);   // y @ PERM(i)
      float* pd = outp + row * 2048 + 2 * i;     // slot i <- value @ PERM(i): coalesced
      __hip_atomic_store(pd,     y.x + bv.x, __ATOMIC_RELAXED, __HIP_MEMORY_SCOPE_SYSTEM);
      __hip_atomic_store(pd + 1, y.y + bv.y, __ATOMIC_RELAXED, __HIP_MEMORY_SCOPE_SYSTEM);
      __syncthreads();   // vmcnt drain before flag
      if (tid == 0)
        __hip_atomic_fetch_add(&wcnt[k], 1, __ATOMIC_RELAXED, __HIP_MEMORY_SCOPE_SYSTEM);
    }
  } else {
    // ---------------- gemm producer: ONE 128x64 tile, K split 4 ways ----------------
    const int q = bid - 144;                 // [0,4096)
    const int g = tid >> 8, tid8 = tid & 255;
    const int m0 = (q >> 5) * 128, n0 = (q & 31) * 64;
    unsigned short* As = (unsigned short*)(smem + g * 15360);   // 128 x 40 (padded)
    unsigned short* Bs = As + 5120;                             // 64 x 40
    const int lane = tid8 & 63, wave = tid8 >> 6;
    const int srA = tid8 >> 1, scA = (tid8 & 1) << 4;
    const int srB = tid8 >> 2, scB = (tid8 & 3) << 3;
    const float* gaf = x  + (size_t)(m0 + srA) * 2048 + scA + g * 512;
    const float* gbf = Wg + (size_t)(n0 + srB) * 2048 + scB + g * 512;
    unsigned short* la = As + srA * 40 + scA;
    unsigned short* lb = Bs + srB * 40 + scB;
    float af[32];
    #pragma unroll
    for (int j = 0; j < 32; ++j) af[j] = 0.f;
    {
      f32x4 acc[2][4];
      #pragma unroll
      for (int m = 0; m < 2; ++m)
        #pragma unroll
        for (int n = 0; n < 4; ++n)
          acc[m][n] = f32x4{0.f, 0.f, 0.f, 0.f};
      const int arow = wave * 32 + (lane & 15);
      const int brow = lane & 15;
      const int koff = (lane >> 4) * 8;
      for (int ks = 0; ks < 16; ++ks){
        const int k0 = ks * 32;
        float4 f0 = *(const float4*)(gaf + k0);
        float4 f1 = *(const float4*)(gaf + k0 + 4);
        float4 f2 = *(const float4*)(gaf + k0 + 8);
        float4 f3 = *(const float4*)(gaf + k0 + 12);
        float4 g0 = *(const float4*)(gbf + k0);
        float4 g1 = *(const float4*)(gbf + k0 + 4);
        u32x4 pa0, pa1, pbv;
        pa0[0] = cvtpk(f0.x, f0.y); pa0[1] = cvtpk(f0.z, f0.w);
        pa0[2] = cvtpk(f1.x, f1.y); pa0[3] = cvtpk(f1.z, f1.w);
        pa1[0] = cvtpk(f2.x, f2.y); pa1[1] = cvtpk(f2.z, f2.w);
        pa1[2] = cvtpk(f3.x, f3.y); pa1[3] = cvtpk(f3.z, f3.w);
        pbv[0] = cvtpk(g0.x, g0.y); pbv[1] = cvtpk(g0.z, g0.w);
        pbv[2] = cvtpk(g1.x, g1.y); pbv[3] = cvtpk(g1.z, g1.w);
        __syncthreads();
        *(u32x4*)(la)     = pa0;
        *(u32x4*)(la + 8) = pa1;
        *(u32x4*)(lb)     = pbv;
        __syncthreads();
        bf16x8 av[2], bvv[4];
        #pragma unroll
        for (int m = 0; m < 2; ++m) av[m] = *(const bf16x8*)(As + (arow + m * 16) * 40 + koff);
        #pragma unroll
        for (int n = 0; n < 4; ++n) bvv[n] = *(const bf16x8*)(Bs + (brow + n * 16) * 40 + koff);
        #pragma unroll
        for (int m = 0; m < 2; ++m)
          #pragma unroll
          for (int n = 0; n < 4; ++n)
            acc[m][n] = __builtin_amdgcn_mfma_f32_16x16x32_bf16(av[m], bvv[n], acc[m][n], 0, 0, 0);
      }
      #pragma unroll
      for (int m = 0; m < 2; ++m)
        #pragma unroll
        for (int n = 0; n < 4; ++n)
          #pragma unroll
          for (int r = 0; r < 4; ++r)
            af[(m * 4 + n) * 4 + r] = acc[m][n][r];
    }
    // ---- LDS tree reduction across the 4 K-groups (conflict-free layout) ----
    __syncthreads();
    float* red = (float*)smem;
    if (g == 1){
      #pragma unroll
      for (int j = 0; j < 32; ++j) red[j * 256 + tid8] = af[j];
    } else if (g == 3){
      #pragma unroll
      for (int j = 0; j < 32; ++j) red[8192 + j * 256 + tid8] = af[j];
    }
    __syncthreads();
    if (g == 0){
      #pragma unroll
      for (int j = 0; j < 32; ++j) af[j] += red[j * 256 + tid8];
    } else if (g == 2){
      #pragma unroll
      for (int j = 0; j < 32; ++j) af[j] += red[8192 + j * 256 + tid8];
    }
    __syncthreads();
    if (g == 2){
      #pragma unroll
      for (int j = 0; j < 32; ++j) red[j * 256 + tid8] = af[j];
    }
    __syncthreads();
    if (g == 0){
      #pragma unroll
      for (int j = 0; j < 32; ++j) af[j] += red[j * 256 + tid8];
      // silu + PERM-layout stores: float ng -> column 2*PERMF(ng>>1) + (ng&1)
      #pragma unroll
      for (int n = 0; n < 4; ++n){
        const int ng = n0 + n * 16 + (lane & 15);
        const int col = 2 * PERMF(ng >> 1) + (ng & 1);
        const float bgv = bg[ng];
        #pragma unroll
        for (int m = 0; m < 2; ++m){
          const int mbase = m0 + wave * 32 + m * 16 + (lane >> 4) * 4;
          #pragma unroll
          for (int r = 0; r < 4; ++r){
            float v = af[(m * 4 + n) * 4 + r] + bgv;
            float s = v / (1.0f + __expf(-v));
            __hip_atomic_store(&houtp[(size_t)(mbase + r + 16) * 2048 + col], s,
                               __ATOMIC_RELAXED, __HIP_MEMORY_SCOPE_SYSTEM);
          }
        }
      }
    }
    __syncthreads();   // vmcnt drain before flag
    if (tid == 0)
      __hip_atomic_fetch_add(&gcnt[q >> 5], 1, __ATOMIC_RELAXED, __HIP_MEMORY_SCOPE_SYSTEM);
  }
}

extern "C" void kernel_launch(void* const* d_in, const int* in_sizes, int n_in,
                              void* d_out, int out_size, void* d_ws, size_t ws_size,
                              hipStream_t stream){
  const float* x  = (const float*)d_in[0];
  const float* h0 = (const float*)d_in[1];
  const float* ch = (const float*)d_in[2];
  const float* cx = (const float*)d_in[3];
  const float* Wg = (const float*)d_in[4];
  const float* bb = (const float*)d_in[5];
  const float* bg = (const float*)d_in[6];
  float* outp  = (float*)d_out;                        // [T,B,D]
  float* houtp = outp + (size_t)1024 * 16 * 2048;      // [T+1,B,D]

  int* flags = (int*)d_ws;   // 256 ints
  hipMemsetAsync(flags, 0, 256 * sizeof(int), stream);
  mega<<<dim3(4240), dim3(1024), 0, stream>>>(x, Wg, h0, ch, cx, bb, bg,
                                              outp, houtp, flags);
}

// Round 11
// 2361.604 us; speedup vs baseline: 1.2567x; 1.2567x over previous
//
#include <hip/hip_runtime.h>
#include <hip/hip_bf16.h>

// CirculantElmanCell: T=1024, B=16, D=2048
// out0: output [T,B,D] f32 ; out1: h [T+1,B,D] f32 (concatenated in d_out)

typedef __attribute__((ext_vector_type(8))) unsigned short us8;
typedef __attribute__((ext_vector_type(8))) __bf16 bf16x8;
typedef __attribute__((ext_vector_type(4))) float f32x4;

__device__ __forceinline__ int SIGF(int a){ return a ^ (((a >> 8) & 3) << 2) ^ ((a >> 6) & 3); }
__device__ __forceinline__ int rev2i(int v){ return ((v & 1) << 1) | ((v >> 1) & 1); }
__device__ __forceinline__ int PERMF(int i){
  return rev2i((i >> 8) & 3) | (rev2i((i >> 6) & 3) << 2) | (rev2i((i >> 4) & 3) << 4)
       | (rev2i((i >> 2) & 3) << 6) | (rev2i(i & 3) << 8);
}

// LDS-only barrier: no vmcnt drain (global loads/stores stay in flight)
#define LDSBAR() do { \
  asm volatile("s_waitcnt lgkmcnt(0)\n\ts_barrier" ::: "memory"); \
  __builtin_amdgcn_sched_barrier(0); \
} while (0)

__device__ __forceinline__ unsigned short f2bf(float f){
  unsigned int u = __float_as_uint(f);
  return (unsigned short)((u + 0x7FFFu + ((u >> 16) & 1u)) >> 16);
}

__device__ __forceinline__ void sincos2pi(float fr, float& sn, float& co){
#if __has_builtin(__builtin_amdgcn_sinf) && __has_builtin(__builtin_amdgcn_cosf)
  sn = __builtin_amdgcn_sinf(fr);   // v_sin_f32: revolutions
  co = __builtin_amdgcn_cosf(fr);
#else
  __sincosf(fr * 6.28318530717958647692f, &sn, &co);
#endif
}

__device__ __forceinline__ float2 cmul(float2 a, float2 b){
  return make_float2(a.x*b.x - a.y*b.y, a.x*b.y + a.y*b.x);
}
__device__ __forceinline__ float2 cmulc(float2 a, float2 b){   // a * conj(b)
  return make_float2(a.x*b.x + a.y*b.y, a.y*b.x - a.x*b.y);
}
__device__ __forceinline__ float2 cadd(float2 a, float2 b){ return make_float2(a.x+b.x, a.y+b.y); }
__device__ __forceinline__ float2 csub(float2 a, float2 b){ return make_float2(a.x-b.x, a.y-b.y); }

__device__ __forceinline__ float tanh_fast(float x){
  float e = __expf(2.0f * x);
  return 1.0f - 2.0f / (e + 1.0f);
}

__device__ __forceinline__ float2 wn(int num, float dinv, int sgn){
  float sn, co; sincos2pi((float)num * dinv, sn, co);
  return make_float2(co, sgn > 0 ? sn : -sn);
}

// ---------------- cross-lane exchange primitives ----------------
template<int CTRL>
__device__ __forceinline__ float2 dpp2(float2 v){
  float2 r;
  r.x = __int_as_float(__builtin_amdgcn_mov_dpp(__float_as_int(v.x), CTRL, 0xF, 0xF, true));
  r.y = __int_as_float(__builtin_amdgcn_mov_dpp(__float_as_int(v.y), CTRL, 0xF, 0xF, true));
  return r;
}
template<int IMM>
__device__ __forceinline__ float2 swz2(float2 v){
  float2 r;
  r.x = __int_as_float(__builtin_amdgcn_ds_swizzle(__float_as_int(v.x), IMM));
  r.y = __int_as_float(__builtin_amdgcn_ds_swizzle(__float_as_int(v.y), IMM));
  return r;
}
__device__ __forceinline__ float2 bperm2(int addr, float2 v){
  float2 r;
  r.x = __int_as_float(__builtin_amdgcn_ds_bpermute(addr, __float_as_int(v.x)));
  r.y = __int_as_float(__builtin_amdgcn_ds_bpermute(addr, __float_as_int(v.y)));
  return r;
}
#define DPP_XOR1 0xB1  // quad_perm [1,0,3,2]
#define DPP_XOR2 0x4E  // quad_perm [2,3,0,1]

// ---------------- folded butterfly core (verified R9/R10) ----------------
template<int CONJ>
__device__ __forceinline__ float2 fold2(float2 u, float2 v, float2 C1, float2 C2){
  float2 r;
  if (!CONJ){
    r.x = u.x*C1.x - u.y*C1.y + v.x*C2.x - v.y*C2.y;
    r.y = u.x*C1.y + u.y*C1.x + v.x*C2.y + v.y*C2.x;
  } else {
    r.x = u.x*C1.x + u.y*C1.y + v.x*C2.x + v.y*C2.y;
    r.y = u.y*C1.x - u.x*C1.y + v.y*C2.x - v.x*C2.y;
  }
  return r;
}

template<int POS>
__device__ __forceinline__ float2 lds4f(const float2* buf, int a0, int a1, int a2, int a3,
                                        float sB, float2 C1, float2 C2){
  float2 in0 = buf[a0], in1 = buf[a1], in2 = buf[a2], in3 = buf[a3];
  float2 u = make_float2(fmaf(sB, in2.x, in0.x), fmaf(sB, in2.y, in0.y));
  float2 v = make_float2(fmaf(sB, in3.x, in1.x), fmaf(sB, in3.y, in1.y));
  return fold2<POS>(u, v, C1, C2);
}

template<int POS>
__device__ __forceinline__ float2 lanes3f(float2 T, int bpa,
    float sH2, float2 E1, float2 E2,
    float sH3, float2 F1, float2 F2,
    float sH4, float2 G1, float2 G2){
  { float2 par = bperm2(bpa, T);
    T.x = fmaf(sH2, T.x, par.x); T.y = fmaf(sH2, T.y, par.y);
    float2 p2 = swz2<0x401F>(T);
    T = fold2<POS>(T, p2, E1, E2); }
  { float2 par = swz2<0x201F>(T);
    T.x = fmaf(sH3, T.x, par.x); T.y = fmaf(sH3, T.y, par.y);
    float2 p2 = swz2<0x101F>(T);
    T = fold2<POS>(T, p2, F1, F2); }
  { float2 par = dpp2<DPP_XOR2>(T);
    T.x = fmaf(sH4, T.x, par.x); T.y = fmaf(sH4, T.y, par.y);
    float2 p2 = dpp2<DPP_XOR1>(T);
    T = fold2<POS>(T, p2, G1, G2); }
  return T;
}

// ---------------- per-thread constants ----------------
struct TW {
  float2 A1, A2, B1, B2;
  float2 E1, E2, F1, F2, G1, G2;
  float2 wmd;
  float sB0, sB1, sH2, sH3, sH4;
  int sfi, swP, smir, bpa;
  int aA0, aA1, aA2, aA3, aB0, aB1, aB2, aB3;
};

__device__ __forceinline__ float2 scal(float2 a, float s){ return make_float2(a.x*s, a.y*s); }

__device__ __forceinline__ void make_tw(int i, TW& S){
  const int p0 = rev2i((i >> 8) & 3);
  const int p1 = rev2i((i >> 6) & 3);
  const int p2v = rev2i((i >> 4) & 3);
  const int p3v = rev2i((i >> 2) & 3);
  const float2 tw0 = wn(((i & 255) * p0) & 1023, 1.0f/1024.0f, -1);
  const float2 tw1 = wn(((i & 63) * p1) & 255, 1.0f/256.0f, -1);
  const float2 tw2 = wn(((i & 15) * p2v) & 63, 1.0f/64.0f, -1);
  const float2 tw3 = wn(((i & 3) * p3v) & 15, 1.0f/16.0f, -1);
  S.wmd = wn(i & 2047, 1.0f/2048.0f, -1);
  const float sD0 = (p0 & 2) ? -1.f : 1.f;  const bool sel0 = p0 & 1;
  const float sD1 = (p1 & 2) ? -1.f : 1.f;  const bool sel1 = p1 & 1;
  S.sB0 = (p0 & 1) ? -1.f : 1.f;
  S.sB1 = (p1 & 1) ? -1.f : 1.f;
  const float2 rho0 = sel0 ? make_float2(0.f,-1.f) : make_float2(1.f,0.f);
  const float2 rho1 = sel1 ? make_float2(0.f,-1.f) : make_float2(1.f,0.f);
  S.A1 = tw0; S.A2 = scal(cmul(tw0, rho0), sD0);
  S.B1 = tw1; S.B2 = scal(cmul(tw1, rho1), sD1);
  const bool c02 = (i >> 4) & 1, c12 = (i >> 5) & 1;
  const bool c03 = (i >> 2) & 1, c13 = (i >> 3) & 1;
  const bool c04 = i & 1,        c14 = (i >> 1) & 1;
  S.sH2 = c12 ? -1.f : 1.f;
  S.sH3 = c13 ? -1.f : 1.f;
  S.sH4 = c14 ? -1.f : 1.f;
  {
    const float sL = c02 ? -1.f : 1.f;
    const float2 rho = c12 ? make_float2(0.f,-1.f) : make_float2(1.f,0.f);
    const float2 al = c02 ? scal(rho, sL) : make_float2(1.f,0.f);
    const float2 be = c02 ? make_float2(1.f,0.f) : scal(rho, sL);
    S.E1 = cmul(tw2, al); S.E2 = cmul(tw2, be);
  }
  {
    const float sL = c03 ? -1.f : 1.f;
    const float2 rho = c13 ? make_float2(0.f,-1.f) : make_float2(1.f,0.f);
    const float2 al = c03 ? scal(rho, sL) : make_float2(1.f,0.f);
    const float2 be = c03 ? make_float2(1.f,0.f) : scal(rho, sL);
    S.F1 = cmul(tw3, al); S.F2 = cmul(tw3, be);
  }
  {
    const float sL = c04 ? -1.f : 1.f;
    const float2 rho = c14 ? make_float2(0.f,-1.f) : make_float2(1.f,0.f);
    S.G1 = c04 ? scal(rho, sL) : make_float2(1.f,0.f);
    S.G2 = c04 ? make_float2(1.f,0.f) : scal(rho, sL);
  }
  S.sfi = SIGF(i); S.swP = SIGF(PERMF(i)); S.smir = SIGF((1024 - i) & 1023);
  S.bpa = ((i & 63) ^ 32) << 2;
  const int r256 = i & 255;
  S.aA0 = SIGF(r256); S.aA1 = SIGF(r256 + 256); S.aA2 = SIGF(r256 + 512); S.aA3 = SIGF(r256 + 768);
  const int b64 = (i & ~255) + (i & 63);
  S.aB0 = SIGF(b64); S.aB1 = SIGF(b64 + 64); S.aB2 = SIGF(b64 + 128); S.aB3 = SIGF(b64 + 192);
}

// full conv body (R9-verified): fwd FFT, spectral multiply, inv FFT; result at bA[S.sfi]
__device__ __forceinline__ void fftconv(float2* hz, float2* bA, float2* bB,
                                        const TW& S, float2 P, float2 Q){
  float2 T = lds4f<0>(hz, S.aA0, S.aA1, S.aA2, S.aA3, S.sB0, S.A1, S.A2);
  bA[S.sfi] = T; LDSBAR();
  T = lds4f<0>(bA, S.aB0, S.aB1, S.aB2, S.aB3, S.sB1, S.B1, S.B2);
  T = lanes3f<0>(T, S.bpa, S.sH2, S.E1, S.E2, S.sH3, S.F1, S.F2, S.sH4, S.G1, S.G2);
  bB[S.swP] = T; LDSBAR();
  {
    float2 zk = bB[S.sfi], zp = bB[S.smir];
    bA[S.sfi] = cadd(cmul(P, zk), cmulc(Q, zp));
  }
  LDSBAR();
  T = lds4f<1>(bA, S.aA0, S.aA1, S.aA2, S.aA3, S.sB0, S.A1, S.A2);
  bB[S.sfi] = T; LDSBAR();
  T = lds4f<1>(bB, S.aB0, S.aB1, S.aB2, S.aB3, S.sB1, S.B1, S.B2);
  T = lanes3f<1>(T, S.bpa, S.sH2, S.E1, S.E2, S.sH3, S.F1, S.F2, S.sH4, S.G1, S.G2);
  bA[S.swP] = T; LDSBAR();
}

// in-block lam + P/Q from real 2048-seq c (verified R9/R10)
__device__ __forceinline__ void make_PQ(const float* __restrict__ c, int i, const TW& S,
                                        float2* hz, float2* bA, float2* bB,
                                        float2& P, float2& Q){
  hz[S.sfi] = ((const float2*)c)[i];
  __syncthreads();
  float2 T = lds4f<0>(hz, S.aA0, S.aA1, S.aA2, S.aA3, S.sB0, S.A1, S.A2);
  bA[S.sfi] = T;
  __syncthreads();
  T = lds4f<0>(bA, S.aB0, S.aB1, S.aB2, S.aB3, S.sB1, S.B1, S.B2);
  T = lanes3f<0>(T, S.bpa, S.sH2, S.E1, S.E2, S.sH3, S.F1, S.F2, S.sH4, S.G1, S.G2);
  bB[S.swP] = T;
  __syncthreads();
  float2 zk = bB[S.sfi], zp = bB[S.smir];
  float2 E = make_float2(0.5f*(zk.x+zp.x),  0.5f*(zk.y-zp.y));
  float2 O = make_float2(0.5f*(zk.y+zp.y), -0.5f*(zk.x-zp.x));
  float2 w = S.wmd;
  float2 wO = cmul(w, O);
  float2 lamA = scal(cadd(E, wO), 1.0f/2048.0f);
  float2 lamB = scal(csub(E, wO), 1.0f/2048.0f);
  float2 al = make_float2(0.5f*(1.0f + w.y), -0.5f*w.x);
  float2 be = make_float2(0.5f*(1.0f - w.y),  0.5f*w.x);
  float2 ga = make_float2(1.0f + w.y,  w.x);
  float2 de = make_float2(1.0f - w.y, -w.x);
  float2 gA = cmul(ga, lamA), dB = cmul(de, lamB);
  P = cadd(cmul(gA, al), cmul(dB, be));
  Q = cadd(cmul(gA, be), cmul(dB, al));
  __syncthreads();
}

// ---------------- f32 -> bf16 bulk convert (R8-proven) ----------------
__global__ __launch_bounds__(256) void cvt_bf16(const float* __restrict__ in,
                                                unsigned short* __restrict__ out, int n8){
  int i = blockIdx.x * 256 + threadIdx.x;
  if (i >= n8) return;
  float4 a = ((const float4*)in)[2 * i];
  float4 b = ((const float4*)in)[2 * i + 1];
  us8 r;
  r[0] = f2bf(a.x); r[1] = f2bf(a.y); r[2] = f2bf(a.z); r[3] = f2bf(a.w);
  r[4] = f2bf(b.x); r[5] = f2bf(b.y); r[6] = f2bf(b.z); r[7] = f2bf(b.w);
  ((us8*)out)[i] = r;
}

// =====================================================================
// mega v6 = R8 structure + R9 micro-wins (fold2, in-block lam).
// blocks [0,16) recur ; [16,144) circx ; [144,1168) gemm (4 tiles each, bf16).
// Producer->consumer: sc1 system-scope stores/loads + relaxed system flags.
// 96KB static LDS -> 1 block/CU.
// =====================================================================
__global__ __launch_bounds__(1024, 4) void mega(
    const float* __restrict__ x, const unsigned short* __restrict__ xb,
    const unsigned short* __restrict__ Wb, const float* __restrict__ h0,
    const float* __restrict__ ch, const float* __restrict__ cx,
    const float* __restrict__ bias, const float* __restrict__ bg,
    float* __restrict__ outp, float* __restrict__ houtp, int* __restrict__ flags){
  __shared__ __align__(16) char smem[98304];   // 96KB: forces 1 block/CU
  const int bid = blockIdx.x;
  const int tid = threadIdx.x;
  int* gcnt = flags;
  int* wcnt = flags + 128;

  if (bid < 16){
    // ---------------- recur consumer (dedicated CU) ----------------
    float2* hz = (float2*)smem; float2* bA = hz + 1024; float2* bB = hz + 2048;
    const int i = tid, b = bid;
    TW S; make_tw(i, S);
    float2 P, Q; make_PQ(ch, i, S, hz, bA, bB, P, Q);
    {
      const float2* h02 = (const float2*)(h0 + (size_t)b * 2048);
      float2* hrow0 = (float2*)(houtp + (size_t)b * 2048);
      float2 v = h02[i]; hz[S.sfi] = v; hrow0[i] = v;
    }
    __syncthreads();
    #pragma unroll 1
    for (int t = 0; t < 1024; ++t){
      if ((t & 7) == 0){
        if (tid == 0){
          const int xk = t >> 3;
          while (__hip_atomic_load(&gcnt[xk], __ATOMIC_RELAXED, __HIP_MEMORY_SCOPE_SYSTEM) < 32)
            __builtin_amdgcn_s_sleep(16);
          while (__hip_atomic_load(&wcnt[xk], __ATOMIC_RELAXED, __HIP_MEMORY_SCOPE_SYSTEM) < 128)
            __builtin_amdgcn_s_sleep(16);
        }
        __syncthreads();
      }
      float* orow = outp  + ((size_t)t * 16 + b) * 2048;
      float* hrow = houtp + ((size_t)(t + 1) * 16 + b) * 2048;
      float2 pr, gv;   // system-scope (L2-bypass) loads from L3
      pr.x = __hip_atomic_load(orow + 2*i,     __ATOMIC_RELAXED, __HIP_MEMORY_SCOPE_SYSTEM);
      pr.y = __hip_atomic_load(orow + 2*i + 1, __ATOMIC_RELAXED, __HIP_MEMORY_SCOPE_SYSTEM);
      gv.x = __hip_atomic_load(hrow + 2*i,     __ATOMIC_RELAXED, __HIP_MEMORY_SCOPE_SYSTEM);
      gv.y = __hip_atomic_load(hrow + 2*i + 1, __ATOMIC_RELAXED, __HIP_MEMORY_SCOPE_SYSTEM);
      fftconv(hz, bA, bB, S, P, Q);
      float2 y = bA[S.sfi];
      float hx = tanh_fast(y.x + pr.x);
      float hy = tanh_fast(y.y + pr.y);
      float ox = hx * gv.x, oy = hy * gv.y;
      asm volatile("" : "+v"(hx), "+v"(hy) : "v"(gv.x), "v"(gv.y));
      float2 hv = make_float2(hx, hy);
      hz[S.sfi] = hv;
      *(float2*)(hrow + 2 * i) = hv;
      *(float2*)(orow + 2 * i) = make_float2(ox, oy);
      LDSBAR();
    }
  } else if (bid < 144){
    // ---------------- circx producer: rows cblk + 128*k ----------------
    float2* hz = (float2*)smem; float2* bA = hz + 1024; float2* bB = hz + 2048;
    const int i = tid, cblk = bid - 16;
    TW S; make_tw(i, S);
    float2 P, Q; make_PQ(cx, i, S, hz, bA, bB, P, Q);
    const float2 bv = ((const float2*)bias)[i];
    #pragma unroll 1
    for (int k = 0; k < 128; ++k){
      const size_t row = (size_t)cblk + ((size_t)k << 7);
      hz[S.sfi] = ((const float2*)(x + row * 2048))[i];
      LDSBAR();
      fftconv(hz, bA, bB, S, P, Q);
      float2 y = bA[S.sfi];
      float* pd = outp + row * 2048 + 2 * i;
      __hip_atomic_store(pd,     y.x + bv.x, __ATOMIC_RELAXED, __HIP_MEMORY_SCOPE_SYSTEM);
      __hip_atomic_store(pd + 1, y.y + bv.y, __ATOMIC_RELAXED, __HIP_MEMORY_SCOPE_SYSTEM);
      __syncthreads();   // vmcnt(0) drain: stores complete at L3 before flag
      if (tid == 0)
        __hip_atomic_fetch_add(&wcnt[k], 1, __ATOMIC_RELAXED, __HIP_MEMORY_SCOPE_SYSTEM);
    }
  } else {
    // ---------------- gemm producer: 4 tiles 128x64, bf16, LDA=40 pad (R8-proven) ----------------
    const int q = bid - 144;
    const int g = tid >> 8, tid8 = tid & 255;
    const int tau = q * 4 + g;
    const int m0 = (tau >> 5) * 128, n0 = (tau & 31) * 64;
    unsigned short* As = (unsigned short*)(smem + g * 15360);   // 128 x 40 (padded)
    unsigned short* Bs = As + 5120;                             // 64 x 40
    const int lane = tid8 & 63, wave = tid8 >> 6;
    const int srA = tid8 >> 1, scA = (tid8 & 1) << 4;
    const int srB = tid8 >> 2, scB = (tid8 & 3) << 3;
    const unsigned short* ga = xb + (size_t)(m0 + srA) * 2048 + scA;
    const unsigned short* gb = Wb + (size_t)(n0 + srB) * 2048 + scB;
    unsigned short* la = As + srA * 40 + scA;
    unsigned short* lb = Bs + srB * 40 + scB;
    f32x4 acc[2][4];
    #pragma unroll
    for (int m = 0; m < 2; ++m)
      #pragma unroll
      for (int n = 0; n < 4; ++n)
        acc[m][n] = f32x4{0.f, 0.f, 0.f, 0.f};
    const int arow = wave * 32 + (lane & 15);
    const int brow = lane & 15;
    const int koff = (lane >> 4) * 8;
    for (int ks = 0; ks < 64; ++ks){
      const int k0 = ks * 32;
      us8 va0 = *(const us8*)(ga + k0);
      us8 va1 = *(const us8*)(ga + k0 + 8);
      us8 vb0 = *(const us8*)(gb + k0);
      __syncthreads();
      *(us8*)(la)     = va0; *(us8*)(la + 8) = va1;
      *(us8*)(lb)     = vb0;
      __syncthreads();
      bf16x8 av[2], bvv[4];
      #pragma unroll
      for (int m = 0; m < 2; ++m) av[m] = *(const bf16x8*)(As + (arow + m * 16) * 40 + koff);
      #pragma unroll
      for (int n = 0; n < 4; ++n) bvv[n] = *(const bf16x8*)(Bs + (brow + n * 16) * 40 + koff);
      #pragma unroll
      for (int m = 0; m < 2; ++m)
        #pragma unroll
        for (int n = 0; n < 4; ++n)
          acc[m][n] = __builtin_amdgcn_mfma_f32_16x16x32_bf16(av[m], bvv[n], acc[m][n], 0, 0, 0);
    }
    #pragma unroll
    for (int n = 0; n < 4; ++n){
      const int ng = n0 + n * 16 + (lane & 15);
      const float bgv = bg[ng];
      #pragma unroll
      for (int m = 0; m < 2; ++m){
        const int mbase = m0 + wave * 32 + m * 16 + (lane >> 4) * 4;
        #pragma unroll
        for (int r = 0; r < 4; ++r){
          float v = acc[m][n][r] + bgv;
          float s = v / (1.0f + __expf(-v));
          __hip_atomic_store(&houtp[(size_t)(mbase + r + 16) * 2048 + ng], s,
                             __ATOMIC_RELAXED, __HIP_MEMORY_SCOPE_SYSTEM);
        }
      }
    }
    __syncthreads();   // vmcnt(0) drain before flag
    if (tid == 0)
      __hip_atomic_fetch_add(&gcnt[q >> 3], 4, __ATOMIC_RELAXED, __HIP_MEMORY_SCOPE_SYSTEM);
  }
}

extern "C" void kernel_launch(void* const* d_in, const int* in_sizes, int n_in,
                              void* d_out, int out_size, void* d_ws, size_t ws_size,
                              hipStream_t stream){
  const float* x  = (const float*)d_in[0];
  const float* h0 = (const float*)d_in[1];
  const float* ch = (const float*)d_in[2];
  const float* cx = (const float*)d_in[3];
  const float* Wg = (const float*)d_in[4];
  const float* bb = (const float*)d_in[5];
  const float* bg = (const float*)d_in[6];
  float* outp  = (float*)d_out;                        // [T,B,D]
  float* houtp = outp + (size_t)1024 * 16 * 2048;      // [T+1,B,D]

  char* w = (char*)d_ws;
  unsigned short* xb = (unsigned short*)w; w += (size_t)16384 * 2048 * 2;
  unsigned short* Wb = (unsigned short*)w; w += (size_t)2048 * 2048 * 2;
  int* flags = (int*)w; w += 256 * sizeof(int);

  cvt_bf16<<<dim3(16384), dim3(256), 0, stream>>>(x,  xb, 16384 * 2048 / 8);
  cvt_bf16<<<dim3(2048),  dim3(256), 0, stream>>>(Wg, Wb,  2048 * 2048 / 8);
  hipMemsetAsync(flags, 0, 256 * sizeof(int), stream);
  mega<<<dim3(1168), dim3(1024), 0, stream>>>(x, xb, Wb, h0, ch, cx, bb, bg,
                                              outp, houtp, flags);
}

// Round 12
// 2257.730 us; speedup vs baseline: 1.3145x; 1.0460x over previous
//
#include <hip/hip_runtime.h>
#include <hip/hip_bf16.h>

// CirculantElmanCell: T=1024, B=16, D=2048
// out0: output [T,B,D] f32 ; out1: h [T+1,B,D] f32 (concatenated in d_out)

typedef __attribute__((ext_vector_type(8))) unsigned short us8;
typedef __attribute__((ext_vector_type(8))) __bf16 bf16x8;
typedef __attribute__((ext_vector_type(4))) float f32x4;

__device__ __forceinline__ int SIGF(int a){ return a ^ (((a >> 8) & 3) << 2) ^ ((a >> 6) & 3); }
__device__ __forceinline__ int rev2i(int v){ return ((v & 1) << 1) | ((v >> 1) & 1); }
__device__ __forceinline__ int PERMF(int i){
  return rev2i((i >> 8) & 3) | (rev2i((i >> 6) & 3) << 2) | (rev2i((i >> 4) & 3) << 4)
       | (rev2i((i >> 2) & 3) << 6) | (rev2i(i & 3) << 8);
}

// LDS-only barrier: no vmcnt drain (global loads/stores stay in flight)
#define LDSBAR() do { \
  asm volatile("s_waitcnt lgkmcnt(0)\n\ts_barrier" ::: "memory"); \
  __builtin_amdgcn_sched_barrier(0); \
} while (0)

__device__ __forceinline__ unsigned short f2bf(float f){
  unsigned int u = __float_as_uint(f);
  return (unsigned short)((u + 0x7FFFu + ((u >> 16) & 1u)) >> 16);
}

__device__ __forceinline__ void sincos2pi(float fr, float& sn, float& co){
#if __has_builtin(__builtin_amdgcn_sinf) && __has_builtin(__builtin_amdgcn_cosf)
  sn = __builtin_amdgcn_sinf(fr);   // v_sin_f32: revolutions
  co = __builtin_amdgcn_cosf(fr);
#else
  __sincosf(fr * 6.28318530717958647692f, &sn, &co);
#endif
}

__device__ __forceinline__ float2 cmul(float2 a, float2 b){
  return make_float2(a.x*b.x - a.y*b.y, a.x*b.y + a.y*b.x);
}
__device__ __forceinline__ float2 cmulc(float2 a, float2 b){   // a * conj(b)
  return make_float2(a.x*b.x + a.y*b.y, a.y*b.x - a.x*b.y);
}
__device__ __forceinline__ float2 cadd(float2 a, float2 b){ return make_float2(a.x+b.x, a.y+b.y); }
__device__ __forceinline__ float2 csub(float2 a, float2 b){ return make_float2(a.x-b.x, a.y-b.y); }

__device__ __forceinline__ float tanh_fast(float x){
  float e = __expf(2.0f * x);
  return 1.0f - 2.0f / (e + 1.0f);
}

__device__ __forceinline__ float2 wn(int num, float dinv, int sgn){
  float sn, co; sincos2pi((float)num * dinv, sn, co);
  return make_float2(co, sgn > 0 ? sn : -sn);
}

// ---------------- cross-lane exchange primitives ----------------
template<int CTRL>
__device__ __forceinline__ float2 dpp2(float2 v){
  float2 r;
  r.x = __int_as_float(__builtin_amdgcn_mov_dpp(__float_as_int(v.x), CTRL, 0xF, 0xF, true));
  r.y = __int_as_float(__builtin_amdgcn_mov_dpp(__float_as_int(v.y), CTRL, 0xF, 0xF, true));
  return r;
}
template<int IMM>
__device__ __forceinline__ float2 swz2(float2 v){
  float2 r;
  r.x = __int_as_float(__builtin_amdgcn_ds_swizzle(__float_as_int(v.x), IMM));
  r.y = __int_as_float(__builtin_amdgcn_ds_swizzle(__float_as_int(v.y), IMM));
  return r;
}
__device__ __forceinline__ float2 bperm2(int addr, float2 v){
  float2 r;
  r.x = __int_as_float(__builtin_amdgcn_ds_bpermute(addr, __float_as_int(v.x)));
  r.y = __int_as_float(__builtin_amdgcn_ds_bpermute(addr, __float_as_int(v.y)));
  return r;
}
#define DPP_XOR1 0xB1  // quad_perm [1,0,3,2]
#define DPP_XOR2 0x4E  // quad_perm [2,3,0,1]

// ---------------- folded butterfly core (verified R9-R11) ----------------
template<int CONJ>
__device__ __forceinline__ float2 fold2(float2 u, float2 v, float2 C1, float2 C2){
  float2 r;
  if (!CONJ){
    r.x = u.x*C1.x - u.y*C1.y + v.x*C2.x - v.y*C2.y;
    r.y = u.x*C1.y + u.y*C1.x + v.x*C2.y + v.y*C2.x;
  } else {
    r.x = u.x*C1.x + u.y*C1.y + v.x*C2.x + v.y*C2.y;
    r.y = u.y*C1.x - u.x*C1.y + v.y*C2.x - v.x*C2.y;
  }
  return r;
}

template<int POS>
__device__ __forceinline__ float2 lds4f(const float2* buf, int a0, int a1, int a2, int a3,
                                        float sB, float2 C1, float2 C2){
  float2 in0 = buf[a0], in1 = buf[a1], in2 = buf[a2], in3 = buf[a3];
  float2 u = make_float2(fmaf(sB, in2.x, in0.x), fmaf(sB, in2.y, in0.y));
  float2 v = make_float2(fmaf(sB, in3.x, in1.x), fmaf(sB, in3.y, in1.y));
  return fold2<POS>(u, v, C1, C2);
}

template<int POS>
__device__ __forceinline__ float2 lanes3f(float2 T, int bpa,
    float sH2, float2 E1, float2 E2,
    float sH3, float2 F1, float2 F2,
    float sH4, float2 G1, float2 G2){
  { float2 par = bperm2(bpa, T);
    T.x = fmaf(sH2, T.x, par.x); T.y = fmaf(sH2, T.y, par.y);
    float2 p2 = swz2<0x401F>(T);
    T = fold2<POS>(T, p2, E1, E2); }
  { float2 par = swz2<0x201F>(T);
    T.x = fmaf(sH3, T.x, par.x); T.y = fmaf(sH3, T.y, par.y);
    float2 p2 = swz2<0x101F>(T);
    T = fold2<POS>(T, p2, F1, F2); }
  { float2 par = dpp2<DPP_XOR2>(T);
    T.x = fmaf(sH4, T.x, par.x); T.y = fmaf(sH4, T.y, par.y);
    float2 p2 = dpp2<DPP_XOR1>(T);
    T = fold2<POS>(T, p2, G1, G2); }
  return T;
}

// ---------------- per-thread constants ----------------
struct TW {
  float2 A1, A2, B1, B2;
  float2 E1, E2, F1, F2, G1, G2;
  float2 wmd;
  float sB0, sB1, sH2, sH3, sH4;
  int sfi, swP, smir, bpa;
  int aA0, aA1, aA2, aA3, aB0, aB1, aB2, aB3;
  int aM0, aM1, aM2, aM3;            // mirror addresses for fused P3+P4
};

__device__ __forceinline__ float2 scal(float2 a, float s){ return make_float2(a.x*s, a.y*s); }

__device__ __forceinline__ void make_tw(int i, TW& S){
  const int p0 = rev2i((i >> 8) & 3);
  const int p1 = rev2i((i >> 6) & 3);
  const int p2v = rev2i((i >> 4) & 3);
  const int p3v = rev2i((i >> 2) & 3);
  const float2 tw0 = wn(((i & 255) * p0) & 1023, 1.0f/1024.0f, -1);
  const float2 tw1 = wn(((i & 63) * p1) & 255, 1.0f/256.0f, -1);
  const float2 tw2 = wn(((i & 15) * p2v) & 63, 1.0f/64.0f, -1);
  const float2 tw3 = wn(((i & 3) * p3v) & 15, 1.0f/16.0f, -1);
  S.wmd = wn(i & 2047, 1.0f/2048.0f, -1);
  const float sD0 = (p0 & 2) ? -1.f : 1.f;  const bool sel0 = p0 & 1;
  const float sD1 = (p1 & 2) ? -1.f : 1.f;  const bool sel1 = p1 & 1;
  S.sB0 = (p0 & 1) ? -1.f : 1.f;
  S.sB1 = (p1 & 1) ? -1.f : 1.f;
  const float2 rho0 = sel0 ? make_float2(0.f,-1.f) : make_float2(1.f,0.f);
  const float2 rho1 = sel1 ? make_float2(0.f,-1.f) : make_float2(1.f,0.f);
  S.A1 = tw0; S.A2 = scal(cmul(tw0, rho0), sD0);
  S.B1 = tw1; S.B2 = scal(cmul(tw1, rho1), sD1);
  const bool c02 = (i >> 4) & 1, c12 = (i >> 5) & 1;
  const bool c03 = (i >> 2) & 1, c13 = (i >> 3) & 1;
  const bool c04 = i & 1,        c14 = (i >> 1) & 1;
  S.sH2 = c12 ? -1.f : 1.f;
  S.sH3 = c13 ? -1.f : 1.f;
  S.sH4 = c14 ? -1.f : 1.f;
  {
    const float sL = c02 ? -1.f : 1.f;
    const float2 rho = c12 ? make_float2(0.f,-1.f) : make_float2(1.f,0.f);
    const float2 al = c02 ? scal(rho, sL) : make_float2(1.f,0.f);
    const float2 be = c02 ? make_float2(1.f,0.f) : scal(rho, sL);
    S.E1 = cmul(tw2, al); S.E2 = cmul(tw2, be);
  }
  {
    const float sL = c03 ? -1.f : 1.f;
    const float2 rho = c13 ? make_float2(0.f,-1.f) : make_float2(1.f,0.f);
    const float2 al = c03 ? scal(rho, sL) : make_float2(1.f,0.f);
    const float2 be = c03 ? make_float2(1.f,0.f) : scal(rho, sL);
    S.F1 = cmul(tw3, al); S.F2 = cmul(tw3, be);
  }
  {
    const float sL = c04 ? -1.f : 1.f;
    const float2 rho = c14 ? make_float2(0.f,-1.f) : make_float2(1.f,0.f);
    S.G1 = c04 ? scal(rho, sL) : make_float2(1.f,0.f);
    S.G2 = c04 ? make_float2(1.f,0.f) : scal(rho, sL);
  }
  S.sfi = SIGF(i); S.swP = SIGF(PERMF(i)); S.smir = SIGF((1024 - i) & 1023);
  S.bpa = ((i & 63) ^ 32) << 2;
  const int r256 = i & 255;
  S.aA0 = SIGF(r256); S.aA1 = SIGF(r256 + 256); S.aA2 = SIGF(r256 + 512); S.aA3 = SIGF(r256 + 768);
  const int b64 = (i & ~255) + (i & 63);
  S.aB0 = SIGF(b64); S.aB1 = SIGF(b64 + 64); S.aB2 = SIGF(b64 + 128); S.aB3 = SIGF(b64 + 192);
  S.aM0 = SIGF((1024 - r256) & 1023);
  S.aM1 = SIGF((1024 - (r256 + 256)) & 1023);
  S.aM2 = SIGF((1024 - (r256 + 512)) & 1023);
  S.aM3 = SIGF((1024 - (r256 + 768)) & 1023);
}

// 5-phase conv body: P1, P2(+lanes), fused P3+P4 (8 reads, U/V MACs), P5(+lanes).
// Result: y at bB[S.sfi] after return (caller reads, then must barrier).
__device__ __forceinline__ void fftconv5(float2* hz, float2* bA, float2* bB,
                                         const TW& S, const float2* U, const float2* V){
  float2 T = lds4f<0>(hz, S.aA0, S.aA1, S.aA2, S.aA3, S.sB0, S.A1, S.A2);
  bA[S.sfi] = T; LDSBAR();
  T = lds4f<0>(bA, S.aB0, S.aB1, S.aB2, S.aB3, S.sB1, S.B1, S.B2);
  T = lanes3f<0>(T, S.bpa, S.sH2, S.E1, S.E2, S.sH3, S.F1, S.F2, S.sH4, S.G1, S.G2);
  bB[S.swP] = T; LDSBAR();
  {
    // fused P3+P4: T4 = sum_q U_q*Z[n_q] + V_q*conj(Z[m_q])
    float2 z0 = bB[S.aA0], z1 = bB[S.aA1], z2 = bB[S.aA2], z3 = bB[S.aA3];
    float2 m0 = bB[S.aM0], m1 = bB[S.aM1], m2 = bB[S.aM2], m3 = bB[S.aM3];
    float2 y = cmul(U[0], z0);
    y = cadd(y, cmul(U[1], z1));
    y = cadd(y, cmul(U[2], z2));
    y = cadd(y, cmul(U[3], z3));
    y = cadd(y, cmulc(V[0], m0));
    y = cadd(y, cmulc(V[1], m1));
    y = cadd(y, cmulc(V[2], m2));
    y = cadd(y, cmulc(V[3], m3));
    bA[S.sfi] = y;
  }
  LDSBAR();
  T = lds4f<1>(bA, S.aB0, S.aB1, S.aB2, S.aB3, S.sB1, S.B1, S.B2);
  T = lanes3f<1>(T, S.bpa, S.sH2, S.E1, S.E2, S.sH3, S.F1, S.F2, S.sH4, S.G1, S.G2);
  bB[S.swP] = T; LDSBAR();
}

// in-block lam + P/Q from real 2048-seq c (verified R9-R11)
__device__ __forceinline__ void make_PQ(const float* __restrict__ c, int i, const TW& S,
                                        float2* hz, float2* bA, float2* bB,
                                        float2& P, float2& Q){
  hz[S.sfi] = ((const float2*)c)[i];
  __syncthreads();
  float2 T = lds4f<0>(hz, S.aA0, S.aA1, S.aA2, S.aA3, S.sB0, S.A1, S.A2);
  bA[S.sfi] = T;
  __syncthreads();
  T = lds4f<0>(bA, S.aB0, S.aB1, S.aB2, S.aB3, S.sB1, S.B1, S.B2);
  T = lanes3f<0>(T, S.bpa, S.sH2, S.E1, S.E2, S.sH3, S.F1, S.F2, S.sH4, S.G1, S.G2);
  bB[S.swP] = T;
  __syncthreads();
  float2 zk = bB[S.sfi], zp = bB[S.smir];
  float2 E = make_float2(0.5f*(zk.x+zp.x),  0.5f*(zk.y-zp.y));
  float2 O = make_float2(0.5f*(zk.y+zp.y), -0.5f*(zk.x-zp.x));
  float2 w = S.wmd;
  float2 wO = cmul(w, O);
  float2 lamA = scal(cadd(E, wO), 1.0f/2048.0f);
  float2 lamB = scal(csub(E, wO), 1.0f/2048.0f);
  float2 al = make_float2(0.5f*(1.0f + w.y), -0.5f*w.x);
  float2 be = make_float2(0.5f*(1.0f - w.y),  0.5f*w.x);
  float2 ga = make_float2(1.0f + w.y,  w.x);
  float2 de = make_float2(1.0f - w.y, -w.x);
  float2 gA = cmul(ga, lamA), dB = cmul(de, lamB);
  P = cadd(cmul(gA, al), cmul(dB, be));
  Q = cadd(cmul(gA, be), cmul(dB, al));
  __syncthreads();
}

// stage P,Q through LDS (linear) and gather per-thread U/V for the fused phase
__device__ __forceinline__ void make_UV(int i, const TW& S, float2 P, float2 Q,
                                        float2* bA, float2* bB, float2* U, float2* V){
  ((float2*)bB)[i] = P;
  ((float2*)bA)[i] = Q;
  __syncthreads();
  const int r256 = i & 255;
  const float2 cA1 = make_float2(S.A1.x, -S.A1.y);
  const float2 cA2 = make_float2(S.A2.x, -S.A2.y);
  float2 cc[4];
  cc[0] = cA1; cc[1] = cA2; cc[2] = scal(cA1, S.sB0); cc[3] = scal(cA2, S.sB0);
  #pragma unroll
  for (int q = 0; q < 4; ++q){
    const int n = r256 + 256 * q;
    U[q] = cmul(cc[q], ((float2*)bB)[n]);
    V[q] = cmul(cc[q], ((float2*)bA)[n]);
  }
  __syncthreads();
}

// ---------------- f32 -> bf16 bulk convert (R8-proven) ----------------
__global__ __launch_bounds__(256) void cvt_bf16(const float* __restrict__ in,
                                                unsigned short* __restrict__ out, int n8){
  int i = blockIdx.x * 256 + threadIdx.x;
  if (i >= n8) return;
  float4 a = ((const float4*)in)[2 * i];
  float4 b = ((const float4*)in)[2 * i + 1];
  us8 r;
  r[0] = f2bf(a.x); r[1] = f2bf(a.y); r[2] = f2bf(a.z); r[3] = f2bf(a.w);
  r[4] = f2bf(b.x); r[5] = f2bf(b.y); r[6] = f2bf(b.z); r[7] = f2bf(b.w);
  ((us8*)out)[i] = r;
}

// =====================================================================
// mega v7 = R11 + fused P3/P4 (5-phase FFT conv body).
// blocks [0,16) recur ; [16,144) circx ; [144,1168) gemm (4 tiles each, bf16).
// Producer->consumer: sc1 system-scope stores/loads + relaxed system flags.
// 96KB static LDS -> 1 block/CU.
// =====================================================================
__global__ __launch_bounds__(1024, 4) void mega(
    const float* __restrict__ x, const unsigned short* __restrict__ xb,
    const unsigned short* __restrict__ Wb, const float* __restrict__ h0,
    const float* __restrict__ ch, const float* __restrict__ cx,
    const float* __restrict__ bias, const float* __restrict__ bg,
    float* __restrict__ outp, float* __restrict__ houtp, int* __restrict__ flags){
  __shared__ __align__(16) char smem[98304];   // 96KB: forces 1 block/CU
  const int bid = blockIdx.x;
  const int tid = threadIdx.x;
  int* gcnt = flags;
  int* wcnt = flags + 128;

  if (bid < 16){
    // ---------------- recur consumer (dedicated CU) ----------------
    float2* hz = (float2*)smem; float2* bA = hz + 1024; float2* bB = hz + 2048;
    const int i = tid, b = bid;
    TW S; make_tw(i, S);
    float2 P, Q; make_PQ(ch, i, S, hz, bA, bB, P, Q);
    float2 U[4], V[4]; make_UV(i, S, P, Q, bA, bB, U, V);
    {
      const float2* h02 = (const float2*)(h0 + (size_t)b * 2048);
      float2* hrow0 = (float2*)(houtp + (size_t)b * 2048);
      float2 v = h02[i]; hz[S.sfi] = v; hrow0[i] = v;
    }
    __syncthreads();
    #pragma unroll 1
    for (int t = 0; t < 1024; ++t){
      if ((t & 7) == 0){
        if (tid == 0){
          const int xk = t >> 3;
          while (__hip_atomic_load(&gcnt[xk], __ATOMIC_RELAXED, __HIP_MEMORY_SCOPE_SYSTEM) < 32)
            __builtin_amdgcn_s_sleep(16);
          while (__hip_atomic_load(&wcnt[xk], __ATOMIC_RELAXED, __HIP_MEMORY_SCOPE_SYSTEM) < 128)
            __builtin_amdgcn_s_sleep(16);
        }
        __syncthreads();
      }
      float* orow = outp  + ((size_t)t * 16 + b) * 2048;
      float* hrow = houtp + ((size_t)(t + 1) * 16 + b) * 2048;
      float2 pr, gv;   // system-scope (L2-bypass) loads from L3
      pr.x = __hip_atomic_load(orow + 2*i,     __ATOMIC_RELAXED, __HIP_MEMORY_SCOPE_SYSTEM);
      pr.y = __hip_atomic_load(orow + 2*i + 1, __ATOMIC_RELAXED, __HIP_MEMORY_SCOPE_SYSTEM);
      gv.x = __hip_atomic_load(hrow + 2*i,     __ATOMIC_RELAXED, __HIP_MEMORY_SCOPE_SYSTEM);
      gv.y = __hip_atomic_load(hrow + 2*i + 1, __ATOMIC_RELAXED, __HIP_MEMORY_SCOPE_SYSTEM);
      fftconv5(hz, bA, bB, S, U, V);
      float2 y = bB[S.sfi];
      float hx = tanh_fast(y.x + pr.x);
      float hy = tanh_fast(y.y + pr.y);
      float ox = hx * gv.x, oy = hy * gv.y;
      asm volatile("" : "+v"(hx), "+v"(hy) : "v"(gv.x), "v"(gv.y));
      float2 hv = make_float2(hx, hy);
      hz[S.sfi] = hv;
      *(float2*)(hrow + 2 * i) = hv;
      *(float2*)(orow + 2 * i) = make_float2(ox, oy);
      LDSBAR();
    }
  } else if (bid < 144){
    // ---------------- circx producer: rows cblk + 128*k ----------------
    float2* hz = (float2*)smem; float2* bA = hz + 1024; float2* bB = hz + 2048;
    const int i = tid, cblk = bid - 16;
    TW S; make_tw(i, S);
    float2 P, Q; make_PQ(cx, i, S, hz, bA, bB, P, Q);
    float2 U[4], V[4]; make_UV(i, S, P, Q, bA, bB, U, V);
    const float2 bv = ((const float2*)bias)[i];
    #pragma unroll 1
    for (int k = 0; k < 128; ++k){
      const size_t row = (size_t)cblk + ((size_t)k << 7);
      hz[S.sfi] = ((const float2*)(x + row * 2048))[i];
      LDSBAR();
      fftconv5(hz, bA, bB, S, U, V);
      float2 y = bB[S.sfi];
      float* pd = outp + row * 2048 + 2 * i;
      __hip_atomic_store(pd,     y.x + bv.x, __ATOMIC_RELAXED, __HIP_MEMORY_SCOPE_SYSTEM);
      __hip_atomic_store(pd + 1, y.y + bv.y, __ATOMIC_RELAXED, __HIP_MEMORY_SCOPE_SYSTEM);
      __syncthreads();   // vmcnt(0) drain: stores complete at L3 before flag
      if (tid == 0)
        __hip_atomic_fetch_add(&wcnt[k], 1, __ATOMIC_RELAXED, __HIP_MEMORY_SCOPE_SYSTEM);
    }
  } else {
    // ---------------- gemm producer: 4 tiles 128x64, bf16, LDA=40 pad (R8-proven) ----------------
    const int q = bid - 144;
    const int g = tid >> 8, tid8 = tid & 255;
    const int tau = q * 4 + g;
    const int m0 = (tau >> 5) * 128, n0 = (tau & 31) * 64;
    unsigned short* As = (unsigned short*)(smem + g * 15360);   // 128 x 40 (padded)
    unsigned short* Bs = As + 5120;                             // 64 x 40
    const int lane = tid8 & 63, wave = tid8 >> 6;
    const int srA = tid8 >> 1, scA = (tid8 & 1) << 4;
    const int srB = tid8 >> 2, scB = (tid8 & 3) << 3;
    const unsigned short* ga = xb + (size_t)(m0 + srA) * 2048 + scA;
    const unsigned short* gb = Wb + (size_t)(n0 + srB) * 2048 + scB;
    unsigned short* la = As + srA * 40 + scA;
    unsigned short* lb = Bs + srB * 40 + scB;
    f32x4 acc[2][4];
    #pragma unroll
    for (int m = 0; m < 2; ++m)
      #pragma unroll
      for (int n = 0; n < 4; ++n)
        acc[m][n] = f32x4{0.f, 0.f, 0.f, 0.f};
    const int arow = wave * 32 + (lane & 15);
    const int brow = lane & 15;
    const int koff = (lane >> 4) * 8;
    for (int ks = 0; ks < 64; ++ks){
      const int k0 = ks * 32;
      us8 va0 = *(const us8*)(ga + k0);
      us8 va1 = *(const us8*)(ga + k0 + 8);
      us8 vb0 = *(const us8*)(gb + k0);
      __syncthreads();
      *(us8*)(la)     = va0; *(us8*)(la + 8) = va1;
      *(us8*)(lb)     = vb0;
      __syncthreads();
      bf16x8 av[2], bvv[4];
      #pragma unroll
      for (int m = 0; m < 2; ++m) av[m] = *(const bf16x8*)(As + (arow + m * 16) * 40 + koff);
      #pragma unroll
      for (int n = 0; n < 4; ++n) bvv[n] = *(const bf16x8*)(Bs + (brow + n * 16) * 40 + koff);
      #pragma unroll
      for (int m = 0; m < 2; ++m)
        #pragma unroll
        for (int n = 0; n < 4; ++n)
          acc[m][n] = __builtin_amdgcn_mfma_f32_16x16x32_bf16(av[m], bvv[n], acc[m][n], 0, 0, 0);
    }
    #pragma unroll
    for (int n = 0; n < 4; ++n){
      const int ng = n0 + n * 16 + (lane & 15);
      const float bgv = bg[ng];
      #pragma unroll
      for (int m = 0; m < 2; ++m){
        const int mbase = m0 + wave * 32 + m * 16 + (lane >> 4) * 4;
        #pragma unroll
        for (int r = 0; r < 4; ++r){
          float v = acc[m][n][r] + bgv;
          float s = v / (1.0f + __expf(-v));
          __hip_atomic_store(&houtp[(size_t)(mbase + r + 16) * 2048 + ng], s,
                             __ATOMIC_RELAXED, __HIP_MEMORY_SCOPE_SYSTEM);
        }
      }
    }
    __syncthreads();   // vmcnt(0) drain before flag
    if (tid == 0)
      __hip_atomic_fetch_add(&gcnt[q >> 3], 4, __ATOMIC_RELAXED, __HIP_MEMORY_SCOPE_SYSTEM);
  }
}

extern "C" void kernel_launch(void* const* d_in, const int* in_sizes, int n_in,
                              void* d_out, int out_size, void* d_ws, size_t ws_size,
                              hipStream_t stream){
  const float* x  = (const float*)d_in[0];
  const float* h0 = (const float*)d_in[1];
  const float* ch = (const float*)d_in[2];
  const float* cx = (const float*)d_in[3];
  const float* Wg = (const float*)d_in[4];
  const float* bb = (const float*)d_in[5];
  const float* bg = (const float*)d_in[6];
  float* outp  = (float*)d_out;                        // [T,B,D]
  float* houtp = outp + (size_t)1024 * 16 * 2048;      // [T+1,B,D]

  char* w = (char*)d_ws;
  unsigned short* xb = (unsigned short*)w; w += (size_t)16384 * 2048 * 2;
  unsigned short* Wb = (unsigned short*)w; w += (size_t)2048 * 2048 * 2;
  int* flags = (int*)w; w += 256 * sizeof(int);

  cvt_bf16<<<dim3(16384), dim3(256), 0, stream>>>(x,  xb, 16384 * 2048 / 8);
  cvt_bf16<<<dim3(2048),  dim3(256), 0, stream>>>(Wg, Wb,  2048 * 2048 / 8);
  hipMemsetAsync(flags, 0, 256 * sizeof(int), stream);
  mega<<<dim3(1168), dim3(1024), 0, stream>>>(x, xb, Wb, h0, ch, cx, bb, bg,
                                              outp, houtp, flags);
}

// Round 13
// 2060.253 us; speedup vs baseline: 1.4405x; 1.0959x over previous
//
#include <hip/hip_runtime.h>
#include <hip/hip_bf16.h>

// CirculantElmanCell: T=1024, B=16, D=2048
// out0: output [T,B,D] f32 ; out1: h [T+1,B,D] f32 (concatenated in d_out)

typedef __attribute__((ext_vector_type(8))) unsigned short us8;
typedef __attribute__((ext_vector_type(8))) __bf16 bf16x8;
typedef __attribute__((ext_vector_type(4))) float f32x4;
typedef __attribute__((ext_vector_type(2))) float f32x2;

__device__ __forceinline__ int SIGF(int a){ return a ^ (((a >> 8) & 3) << 2) ^ ((a >> 6) & 3); }
__device__ __forceinline__ int rev2i(int v){ return ((v & 1) << 1) | ((v >> 1) & 1); }
__device__ __forceinline__ int PERMF(int i){
  return rev2i((i >> 8) & 3) | (rev2i((i >> 6) & 3) << 2) | (rev2i((i >> 4) & 3) << 4)
       | (rev2i((i >> 2) & 3) << 6) | (rev2i(i & 3) << 8);
}

// LDS-only barrier: no vmcnt drain (global loads/stores stay in flight)
#define LDSBAR() do { \
  asm volatile("s_waitcnt lgkmcnt(0)\n\ts_barrier" ::: "memory"); \
  __builtin_amdgcn_sched_barrier(0); \
} while (0)

__device__ __forceinline__ unsigned short f2bf(float f){
  unsigned int u = __float_as_uint(f);
  return (unsigned short)((u + 0x7FFFu + ((u >> 16) & 1u)) >> 16);
}

__device__ __forceinline__ void sincos2pi(float fr, float& sn, float& co){
#if __has_builtin(__builtin_amdgcn_sinf) && __has_builtin(__builtin_amdgcn_cosf)
  sn = __builtin_amdgcn_sinf(fr);   // v_sin_f32: revolutions
  co = __builtin_amdgcn_cosf(fr);
#else
  __sincosf(fr * 6.28318530717958647692f, &sn, &co);
#endif
}

__device__ __forceinline__ float2 cmul(float2 a, float2 b){
  return make_float2(a.x*b.x - a.y*b.y, a.x*b.y + a.y*b.x);
}
__device__ __forceinline__ float2 cmulc(float2 a, float2 b){   // a * conj(b)
  return make_float2(a.x*b.x + a.y*b.y, a.y*b.x - a.x*b.y);
}
__device__ __forceinline__ float2 cadd(float2 a, float2 b){ return make_float2(a.x+b.x, a.y+b.y); }
__device__ __forceinline__ float2 csub(float2 a, float2 b){ return make_float2(a.x-b.x, a.y-b.y); }

__device__ __forceinline__ float tanh_fast(float x){
  float e = __expf(2.0f * x);
  return 1.0f - 2.0f / (e + 1.0f);
}

__device__ __forceinline__ float2 wn(int num, float dinv, int sgn){
  float sn, co; sincos2pi((float)num * dinv, sn, co);
  return make_float2(co, sgn > 0 ? sn : -sn);
}

// ---------------- packed-f32 complex primitives (VOP3P, full-rate on CDNA) ----------------
__device__ __forceinline__ f32x2 tov(float2 a){ f32x2 r; r[0] = a.x; r[1] = a.y; return r; }
__device__ __forceinline__ float2 tof(f32x2 a){ return make_float2(a[0], a[1]); }

// element-wise a*b + c (one VOP3P)
__device__ __forceinline__ float2 pk_fma2(float2 a, float2 b, float2 c){
  f32x2 A = tov(a), B = tov(b), C = tov(c), D;
  asm("v_pk_fma_f32 %0, %1, %2, %3" : "=v"(D) : "v"(A), "v"(B), "v"(C));
  return tof(D);
}
// d = C*z  (complex), 2 VOP3P
__device__ __forceinline__ float2 pk_cmul(float2 C, float2 z){
  f32x2 Cv = tov(C), Zv = tov(z), D;
  asm("v_pk_mul_f32 %0, %1, %2 op_sel:[0,0] op_sel_hi:[1,0]\n\t"
      "v_pk_fma_f32 %0, %1, %2, %0 op_sel:[1,1,0] op_sel_hi:[0,1,1] neg_lo:[1,0,0]"
      : "=&v"(D) : "v"(Cv), "v"(Zv));
  return tof(D);
}
// acc += C*z
__device__ __forceinline__ void pk_cfma(float2& acc, float2 C, float2 z){
  f32x2 A = tov(acc), Cv = tov(C), Zv = tov(z);
  asm("v_pk_fma_f32 %0, %1, %2, %0 op_sel:[0,0,0] op_sel_hi:[1,0,1]\n\t"
      "v_pk_fma_f32 %0, %1, %2, %0 op_sel:[1,1,0] op_sel_hi:[0,1,1] neg_lo:[1,0,0]"
      : "+v"(A) : "v"(Cv), "v"(Zv));
  acc = tof(A);
}
// d = V*conj(m)
__device__ __forceinline__ float2 pk_cmulc(float2 V, float2 m){
  f32x2 Vv = tov(V), Mv = tov(m), D;
  asm("v_pk_mul_f32 %0, %1, %2 op_sel:[0,0] op_sel_hi:[1,0]\n\t"
      "v_pk_fma_f32 %0, %1, %2, %0 op_sel:[1,1,0] op_sel_hi:[0,1,1] neg_hi:[1,0,0]"
      : "=&v"(D) : "v"(Vv), "v"(Mv));
  return tof(D);
}
// acc += V*conj(m)
__device__ __forceinline__ void pk_cfmac(float2& acc, float2 V, float2 m){
  f32x2 A = tov(acc), Vv = tov(V), Mv = tov(m);
  asm("v_pk_fma_f32 %0, %1, %2, %0 op_sel:[0,0,0] op_sel_hi:[1,0,1]\n\t"
      "v_pk_fma_f32 %0, %1, %2, %0 op_sel:[1,1,0] op_sel_hi:[0,1,1] neg_hi:[1,0,0]"
      : "+v"(A) : "v"(Vv), "v"(Mv));
  acc = tof(A);
}

// ---------------- cross-lane exchange primitives ----------------
template<int CTRL>
__device__ __forceinline__ float2 dpp2(float2 v){
  float2 r;
  r.x = __int_as_float(__builtin_amdgcn_mov_dpp(__float_as_int(v.x), CTRL, 0xF, 0xF, true));
  r.y = __int_as_float(__builtin_amdgcn_mov_dpp(__float_as_int(v.y), CTRL, 0xF, 0xF, true));
  return r;
}
template<int IMM>
__device__ __forceinline__ float2 swz2(float2 v){
  float2 r;
  r.x = __int_as_float(__builtin_amdgcn_ds_swizzle(__float_as_int(v.x), IMM));
  r.y = __int_as_float(__builtin_amdgcn_ds_swizzle(__float_as_int(v.y), IMM));
  return r;
}
__device__ __forceinline__ float2 bperm2(int addr, float2 v){
  float2 r;
  r.x = __int_as_float(__builtin_amdgcn_ds_bpermute(addr, __float_as_int(v.x)));
  r.y = __int_as_float(__builtin_amdgcn_ds_bpermute(addr, __float_as_int(v.y)));
  return r;
}
#define DPP_XOR1 0xB1  // quad_perm [1,0,3,2]
#define DPP_XOR2 0x4E  // quad_perm [2,3,0,1]

// ---------------- folded butterfly core: now packed (same math as R9-R12) ----------------
template<int CONJ>
__device__ __forceinline__ float2 fold2(float2 u, float2 v, float2 C1, float2 C2){
  if (!CONJ){
    float2 d = pk_cmul(C1, u);   // u*C1
    pk_cfma(d, C2, v);           // + v*C2
    return d;
  } else {
    float2 d = pk_cmulc(u, C1);  // u*conj(C1)
    pk_cfmac(d, v, C2);          // + v*conj(C2)
    return d;
  }
}

template<int POS>
__device__ __forceinline__ float2 lds4f(const float2* buf, int a0, int a1, int a2, int a3,
                                        float2 sBv, float2 C1, float2 C2){
  float2 in0 = buf[a0], in1 = buf[a1], in2 = buf[a2], in3 = buf[a3];
  float2 u = pk_fma2(in2, sBv, in0);   // in0 + sB*in2
  float2 v = pk_fma2(in3, sBv, in1);
  return fold2<POS>(u, v, C1, C2);
}

template<int POS>
__device__ __forceinline__ float2 lanes3f(float2 T, int bpa,
    float2 sH2v, float2 E1, float2 E2,
    float2 sH3v, float2 F1, float2 F2,
    float2 sH4v, float2 G1, float2 G2){
  { float2 par = bperm2(bpa, T);
    T = pk_fma2(T, sH2v, par);          // par + sH2*T
    float2 p2 = swz2<0x401F>(T);
    T = fold2<POS>(T, p2, E1, E2); }
  { float2 par = swz2<0x201F>(T);
    T = pk_fma2(T, sH3v, par);
    float2 p2 = swz2<0x101F>(T);
    T = fold2<POS>(T, p2, F1, F2); }
  { float2 par = dpp2<DPP_XOR2>(T);
    T = pk_fma2(T, sH4v, par);
    float2 p2 = dpp2<DPP_XOR1>(T);
    T = fold2<POS>(T, p2, G1, G2); }
  return T;
}

// ---------------- per-thread constants ----------------
struct TW {
  float2 A1, A2, B1, B2;
  float2 E1, E2, F1, F2, G1, G2;
  float2 wmd;
  float2 sB0v, sB1v, sH2v, sH3v, sH4v;
  float sB0;
  int sfi, swP, smir, bpa;
  int aA0, aA1, aA2, aA3, aB0, aB1, aB2, aB3;
  int aM0, aM1, aM2, aM3;            // mirror addresses for fused P3+P4
};

__device__ __forceinline__ float2 scal(float2 a, float s){ return make_float2(a.x*s, a.y*s); }

__device__ __forceinline__ void make_tw(int i, TW& S){
  const int p0 = rev2i((i >> 8) & 3);
  const int p1 = rev2i((i >> 6) & 3);
  const int p2v = rev2i((i >> 4) & 3);
  const int p3v = rev2i((i >> 2) & 3);
  const float2 tw0 = wn(((i & 255) * p0) & 1023, 1.0f/1024.0f, -1);
  const float2 tw1 = wn(((i & 63) * p1) & 255, 1.0f/256.0f, -1);
  const float2 tw2 = wn(((i & 15) * p2v) & 63, 1.0f/64.0f, -1);
  const float2 tw3 = wn(((i & 3) * p3v) & 15, 1.0f/16.0f, -1);
  S.wmd = wn(i & 2047, 1.0f/2048.0f, -1);
  const float sD0 = (p0 & 2) ? -1.f : 1.f;  const bool sel0 = p0 & 1;
  const float sD1 = (p1 & 2) ? -1.f : 1.f;  const bool sel1 = p1 & 1;
  const float sB0 = (p0 & 1) ? -1.f : 1.f;
  const float sB1 = (p1 & 1) ? -1.f : 1.f;
  S.sB0 = sB0;
  S.sB0v = make_float2(sB0, sB0);
  S.sB1v = make_float2(sB1, sB1);
  const float2 rho0 = sel0 ? make_float2(0.f,-1.f) : make_float2(1.f,0.f);
  const float2 rho1 = sel1 ? make_float2(0.f,-1.f) : make_float2(1.f,0.f);
  S.A1 = tw0; S.A2 = scal(cmul(tw0, rho0), sD0);
  S.B1 = tw1; S.B2 = scal(cmul(tw1, rho1), sD1);
  const bool c02 = (i >> 4) & 1, c12 = (i >> 5) & 1;
  const bool c03 = (i >> 2) & 1, c13 = (i >> 3) & 1;
  const bool c04 = i & 1,        c14 = (i >> 1) & 1;
  const float sH2 = c12 ? -1.f : 1.f;
  const float sH3 = c13 ? -1.f : 1.f;
  const float sH4 = c14 ? -1.f : 1.f;
  S.sH2v = make_float2(sH2, sH2);
  S.sH3v = make_float2(sH3, sH3);
  S.sH4v = make_float2(sH4, sH4);
  {
    const float sL = c02 ? -1.f : 1.f;
    const float2 rho = c12 ? make_float2(0.f,-1.f) : make_float2(1.f,0.f);
    const float2 al = c02 ? scal(rho, sL) : make_float2(1.f,0.f);
    const float2 be = c02 ? make_float2(1.f,0.f) : scal(rho, sL);
    S.E1 = cmul(tw2, al); S.E2 = cmul(tw2, be);
  }
  {
    const float sL = c03 ? -1.f : 1.f;
    const float2 rho = c13 ? make_float2(0.f,-1.f) : make_float2(1.f,0.f);
    const float2 al = c03 ? scal(rho, sL) : make_float2(1.f,0.f);
    const float2 be = c03 ? make_float2(1.f,0.f) : scal(rho, sL);
    S.F1 = cmul(tw3, al); S.F2 = cmul(tw3, be);
  }
  {
    const float sL = c04 ? -1.f : 1.f;
    const float2 rho = c14 ? make_float2(0.f,-1.f) : make_float2(1.f,0.f);
    S.G1 = c04 ? scal(rho, sL) : make_float2(1.f,0.f);
    S.G2 = c04 ? make_float2(1.f,0.f) : scal(rho, sL);
  }
  S.sfi = SIGF(i); S.swP = SIGF(PERMF(i)); S.smir = SIGF((1024 - i) & 1023);
  S.bpa = ((i & 63) ^ 32) << 2;
  const int r256 = i & 255;
  S.aA0 = SIGF(r256); S.aA1 = SIGF(r256 + 256); S.aA2 = SIGF(r256 + 512); S.aA3 = SIGF(r256 + 768);
  const int b64 = (i & ~255) + (i & 63);
  S.aB0 = SIGF(b64); S.aB1 = SIGF(b64 + 64); S.aB2 = SIGF(b64 + 128); S.aB3 = SIGF(b64 + 192);
  S.aM0 = SIGF((1024 - r256) & 1023);
  S.aM1 = SIGF((1024 - (r256 + 256)) & 1023);
  S.aM2 = SIGF((1024 - (r256 + 512)) & 1023);
  S.aM3 = SIGF((1024 - (r256 + 768)) & 1023);
}

// 5-phase conv body (R12-verified structure, packed math).
// Result: y at bB[S.sfi] after return (caller reads, then must barrier).
__device__ __forceinline__ void fftconv5(float2* hz, float2* bA, float2* bB,
                                         const TW& S, const float2* U, const float2* V){
  float2 T = lds4f<0>(hz, S.aA0, S.aA1, S.aA2, S.aA3, S.sB0v, S.A1, S.A2);
  bA[S.sfi] = T; LDSBAR();
  T = lds4f<0>(bA, S.aB0, S.aB1, S.aB2, S.aB3, S.sB1v, S.B1, S.B2);
  T = lanes3f<0>(T, S.bpa, S.sH2v, S.E1, S.E2, S.sH3v, S.F1, S.F2, S.sH4v, S.G1, S.G2);
  bB[S.swP] = T; LDSBAR();
  {
    // fused P3+P4: y = sum_q U_q*Z[n_q] + V_q*conj(Z[m_q])
    float2 z0 = bB[S.aA0], z1 = bB[S.aA1], z2 = bB[S.aA2], z3 = bB[S.aA3];
    float2 m0 = bB[S.aM0], m1 = bB[S.aM1], m2 = bB[S.aM2], m3 = bB[S.aM3];
    float2 y = pk_cmul(U[0], z0);
    pk_cfma(y, U[1], z1);
    pk_cfma(y, U[2], z2);
    pk_cfma(y, U[3], z3);
    pk_cfmac(y, V[0], m0);
    pk_cfmac(y, V[1], m1);
    pk_cfmac(y, V[2], m2);
    pk_cfmac(y, V[3], m3);
    bA[S.sfi] = y;
  }
  LDSBAR();
  T = lds4f<1>(bA, S.aB0, S.aB1, S.aB2, S.aB3, S.sB1v, S.B1, S.B2);
  T = lanes3f<1>(T, S.bpa, S.sH2v, S.E1, S.E2, S.sH3v, S.F1, S.F2, S.sH4v, S.G1, S.G2);
  bB[S.swP] = T; LDSBAR();
}

// in-block lam + P/Q from real 2048-seq c (verified R9-R12)
__device__ __forceinline__ void make_PQ(const float* __restrict__ c, int i, const TW& S,
                                        float2* hz, float2* bA, float2* bB,
                                        float2& P, float2& Q){
  hz[S.sfi] = ((const float2*)c)[i];
  __syncthreads();
  float2 T = lds4f<0>(hz, S.aA0, S.aA1, S.aA2, S.aA3, S.sB0v, S.A1, S.A2);
  bA[S.sfi] = T;
  __syncthreads();
  T = lds4f<0>(bA, S.aB0, S.aB1, S.aB2, S.aB3, S.sB1v, S.B1, S.B2);
  T = lanes3f<0>(T, S.bpa, S.sH2v, S.E1, S.E2, S.sH3v, S.F1, S.F2, S.sH4v, S.G1, S.G2);
  bB[S.swP] = T;
  __syncthreads();
  float2 zk = bB[S.sfi], zp = bB[S.smir];
  float2 E = make_float2(0.5f*(zk.x+zp.x),  0.5f*(zk.y-zp.y));
  float2 O = make_float2(0.5f*(zk.y+zp.y), -0.5f*(zk.x-zp.x));
  float2 w = S.wmd;
  float2 wO = cmul(w, O);
  float2 lamA = scal(cadd(E, wO), 1.0f/2048.0f);
  float2 lamB = scal(csub(E, wO), 1.0f/2048.0f);
  float2 al = make_float2(0.5f*(1.0f + w.y), -0.5f*w.x);
  float2 be = make_float2(0.5f*(1.0f - w.y),  0.5f*w.x);
  float2 ga = make_float2(1.0f + w.y,  w.x);
  float2 de = make_float2(1.0f - w.y, -w.x);
  float2 gA = cmul(ga, lamA), dB = cmul(de, lamB);
  P = cadd(cmul(gA, al), cmul(dB, be));
  Q = cadd(cmul(gA, be), cmul(dB, al));
  __syncthreads();
}

// stage P,Q through LDS (linear) and gather per-thread U/V for the fused phase
__device__ __forceinline__ void make_UV(int i, const TW& S, float2 P, float2 Q,
                                        float2* bA, float2* bB, float2* U, float2* V){
  ((float2*)bB)[i] = P;
  ((float2*)bA)[i] = Q;
  __syncthreads();
  const int r256 = i & 255;
  const float2 cA1 = make_float2(S.A1.x, -S.A1.y);
  const float2 cA2 = make_float2(S.A2.x, -S.A2.y);
  float2 cc[4];
  cc[0] = cA1; cc[1] = cA2; cc[2] = scal(cA1, S.sB0); cc[3] = scal(cA2, S.sB0);
  #pragma unroll
  for (int q = 0; q < 4; ++q){
    const int n = r256 + 256 * q;
    U[q] = cmul(cc[q], ((float2*)bB)[n]);
    V[q] = cmul(cc[q], ((float2*)bA)[n]);
  }
  __syncthreads();
}

// ---------------- f32 -> bf16 bulk convert (R8-proven) ----------------
__global__ __launch_bounds__(256) void cvt_bf16(const float* __restrict__ in,
                                                unsigned short* __restrict__ out, int n8){
  int i = blockIdx.x * 256 + threadIdx.x;
  if (i >= n8) return;
  float4 a = ((const float4*)in)[2 * i];
  float4 b = ((const float4*)in)[2 * i + 1];
  us8 r;
  r[0] = f2bf(a.x); r[1] = f2bf(a.y); r[2] = f2bf(a.z); r[3] = f2bf(a.w);
  r[4] = f2bf(b.x); r[5] = f2bf(b.y); r[6] = f2bf(b.z); r[7] = f2bf(b.w);
  ((us8*)out)[i] = r;
}

// =====================================================================
// mega v8 = R12 (5-phase fused) + packed-f32 complex math in the hot path.
// blocks [0,16) recur ; [16,144) circx ; [144,1168) gemm (4 tiles each, bf16).
// Producer->consumer: sc1 system-scope stores/loads + relaxed system flags.
// 96KB static LDS -> 1 block/CU.
// =====================================================================
__global__ __launch_bounds__(1024, 4) void mega(
    const float* __restrict__ x, const unsigned short* __restrict__ xb,
    const unsigned short* __restrict__ Wb, const float* __restrict__ h0,
    const float* __restrict__ ch, const float* __restrict__ cx,
    const float* __restrict__ bias, const float* __restrict__ bg,
    float* __restrict__ outp, float* __restrict__ houtp, int* __restrict__ flags){
  __shared__ __align__(16) char smem[98304];   // 96KB: forces 1 block/CU
  const int bid = blockIdx.x;
  const int tid = threadIdx.x;
  int* gcnt = flags;
  int* wcnt = flags + 128;

  if (bid < 16){
    // ---------------- recur consumer (dedicated CU) ----------------
    float2* hz = (float2*)smem; float2* bA = hz + 1024; float2* bB = hz + 2048;
    const int i = tid, b = bid;
    TW S; make_tw(i, S);
    float2 P, Q; make_PQ(ch, i, S, hz, bA, bB, P, Q);
    float2 U[4], V[4]; make_UV(i, S, P, Q, bA, bB, U, V);
    {
      const float2* h02 = (const float2*)(h0 + (size_t)b * 2048);
      float2* hrow0 = (float2*)(houtp + (size_t)b * 2048);
      float2 v = h02[i]; hz[S.sfi] = v; hrow0[i] = v;
    }
    __syncthreads();
    #pragma unroll 1
    for (int t = 0; t < 1024; ++t){
      if ((t & 7) == 0){
        if (tid == 0){
          const int xk = t >> 3;
          while (__hip_atomic_load(&gcnt[xk], __ATOMIC_RELAXED, __HIP_MEMORY_SCOPE_SYSTEM) < 32)
            __builtin_amdgcn_s_sleep(16);
          while (__hip_atomic_load(&wcnt[xk], __ATOMIC_RELAXED, __HIP_MEMORY_SCOPE_SYSTEM) < 128)
            __builtin_amdgcn_s_sleep(16);
        }
        __syncthreads();
      }
      float* orow = outp  + ((size_t)t * 16 + b) * 2048;
      float* hrow = houtp + ((size_t)(t + 1) * 16 + b) * 2048;
      float2 pr, gv;   // system-scope (L2-bypass) loads from L3
      pr.x = __hip_atomic_load(orow + 2*i,     __ATOMIC_RELAXED, __HIP_MEMORY_SCOPE_SYSTEM);
      pr.y = __hip_atomic_load(orow + 2*i + 1, __ATOMIC_RELAXED, __HIP_MEMORY_SCOPE_SYSTEM);
      gv.x = __hip_atomic_load(hrow + 2*i,     __ATOMIC_RELAXED, __HIP_MEMORY_SCOPE_SYSTEM);
      gv.y = __hip_atomic_load(hrow + 2*i + 1, __ATOMIC_RELAXED, __HIP_MEMORY_SCOPE_SYSTEM);
      fftconv5(hz, bA, bB, S, U, V);
      float2 y = bB[S.sfi];
      float hx = tanh_fast(y.x + pr.x);
      float hy = tanh_fast(y.y + pr.y);
      float ox = hx * gv.x, oy = hy * gv.y;
      asm volatile("" : "+v"(hx), "+v"(hy) : "v"(gv.x), "v"(gv.y));
      float2 hv = make_float2(hx, hy);
      hz[S.sfi] = hv;
      *(float2*)(hrow + 2 * i) = hv;
      *(float2*)(orow + 2 * i) = make_float2(ox, oy);
      LDSBAR();
    }
  } else if (bid < 144){
    // ---------------- circx producer: rows cblk + 128*k ----------------
    float2* hz = (float2*)smem; float2* bA = hz + 1024; float2* bB = hz + 2048;
    const int i = tid, cblk = bid - 16;
    TW S; make_tw(i, S);
    float2 P, Q; make_PQ(cx, i, S, hz, bA, bB, P, Q);
    float2 U[4], V[4]; make_UV(i, S, P, Q, bA, bB, U, V);
    const float2 bv = ((const float2*)bias)[i];
    #pragma unroll 1
    for (int k = 0; k < 128; ++k){
      const size_t row = (size_t)cblk + ((size_t)k << 7);
      hz[S.sfi] = ((const float2*)(x + row * 2048))[i];
      LDSBAR();
      fftconv5(hz, bA, bB, S, U, V);
      float2 y = bB[S.sfi];
      float* pd = outp + row * 2048 + 2 * i;
      __hip_atomic_store(pd,     y.x + bv.x, __ATOMIC_RELAXED, __HIP_MEMORY_SCOPE_SYSTEM);
      __hip_atomic_store(pd + 1, y.y + bv.y, __ATOMIC_RELAXED, __HIP_MEMORY_SCOPE_SYSTEM);
      __syncthreads();   // vmcnt(0) drain: stores complete at L3 before flag
      if (tid == 0)
        __hip_atomic_fetch_add(&wcnt[k], 1, __ATOMIC_RELAXED, __HIP_MEMORY_SCOPE_SYSTEM);
    }
  } else {
    // ---------------- gemm producer: 4 tiles 128x64, bf16, LDA=40 pad (R8-proven) ----------------
    const int q = bid - 144;
    const int g = tid >> 8, tid8 = tid & 255;
    const int tau = q * 4 + g;
    const int m0 = (tau >> 5) * 128, n0 = (tau & 31) * 64;
    unsigned short* As = (unsigned short*)(smem + g * 15360);   // 128 x 40 (padded)
    unsigned short* Bs = As + 5120;                             // 64 x 40
    const int lane = tid8 & 63, wave = tid8 >> 6;
    const int srA = tid8 >> 1, scA = (tid8 & 1) << 4;
    const int srB = tid8 >> 2, scB = (tid8 & 3) << 3;
    const unsigned short* ga = xb + (size_t)(m0 + srA) * 2048 + scA;
    const unsigned short* gb = Wb + (size_t)(n0 + srB) * 2048 + scB;
    unsigned short* la = As + srA * 40 + scA;
    unsigned short* lb = Bs + srB * 40 + scB;
    f32x4 acc[2][4];
    #pragma unroll
    for (int m = 0; m < 2; ++m)
      #pragma unroll
      for (int n = 0; n < 4; ++n)
        acc[m][n] = f32x4{0.f, 0.f, 0.f, 0.f};
    const int arow = wave * 32 + (lane & 15);
    const int brow = lane & 15;
    const int koff = (lane >> 4) * 8;
    for (int ks = 0; ks < 64; ++ks){
      const int k0 = ks * 32;
      us8 va0 = *(const us8*)(ga + k0);
      us8 va1 = *(const us8*)(ga + k0 + 8);
      us8 vb0 = *(const us8*)(gb + k0);
      __syncthreads();
      *(us8*)(la)     = va0; *(us8*)(la + 8) = va1;
      *(us8*)(lb)     = vb0;
      __syncthreads();
      bf16x8 av[2], bvv[4];
      #pragma unroll
      for (int m = 0; m < 2; ++m) av[m] = *(const bf16x8*)(As + (arow + m * 16) * 40 + koff);
      #pragma unroll
      for (int n = 0; n < 4; ++n) bvv[n] = *(const bf16x8*)(Bs + (brow + n * 16) * 40 + koff);
      #pragma unroll
      for (int m = 0; m < 2; ++m)
        #pragma unroll
        for (int n = 0; n < 4; ++n)
          acc[m][n] = __builtin_amdgcn_mfma_f32_16x16x32_bf16(av[m], bvv[n], acc[m][n], 0, 0, 0);
    }
    #pragma unroll
    for (int n = 0; n < 4; ++n){
      const int ng = n0 + n * 16 + (lane & 15);
      const float bgv = bg[ng];
      #pragma unroll
      for (int m = 0; m < 2; ++m){
        const int mbase = m0 + wave * 32 + m * 16 + (lane >> 4) * 4;
        #pragma unroll
        for (int r = 0; r < 4; ++r){
          float v = acc[m][n][r] + bgv;
          float s = v / (1.0f + __expf(-v));
          __hip_atomic_store(&houtp[(size_t)(mbase + r + 16) * 2048 + ng], s,
                             __ATOMIC_RELAXED, __HIP_MEMORY_SCOPE_SYSTEM);
        }
      }
    }
    __syncthreads();   // vmcnt(0) drain before flag
    if (tid == 0)
      __hip_atomic_fetch_add(&gcnt[q >> 3], 4, __ATOMIC_RELAXED, __HIP_MEMORY_SCOPE_SYSTEM);
  }
}

extern "C" void kernel_launch(void* const* d_in, const int* in_sizes, int n_in,
                              void* d_out, int out_size, void* d_ws, size_t ws_size,
                              hipStream_t stream){
  const float* x  = (const float*)d_in[0];
  const float* h0 = (const float*)d_in[1];
  const float* ch = (const float*)d_in[2];
  const float* cx = (const float*)d_in[3];
  const float* Wg = (const float*)d_in[4];
  const float* bb = (const float*)d_in[5];
  const float* bg = (const float*)d_in[6];
  float* outp  = (float*)d_out;                        // [T,B,D]
  float* houtp = outp + (size_t)1024 * 16 * 2048;      // [T+1,B,D]

  char* w = (char*)d_ws;
  unsigned short* xb = (unsigned short*)w; w += (size_t)16384 * 2048 * 2;
  unsigned short* Wb = (unsigned short*)w; w += (size_t)2048 * 2048 * 2;
  int* flags = (int*)w; w += 256 * sizeof(int);

  cvt_bf16<<<dim3(16384), dim3(256), 0, stream>>>(x,  xb, 16384 * 2048 / 8);
  cvt_bf16<<<dim3(2048),  dim3(256), 0, stream>>>(Wg, Wb,  2048 * 2048 / 8);
  hipMemsetAsync(flags, 0, 256 * sizeof(int), stream);
  mega<<<dim3(1168), dim3(1024), 0, stream>>>(x, xb, Wb, h0, ch, cx, bb, bg,
                                              outp, houtp, flags);
}

// Round 14
// 1774.665 us; speedup vs baseline: 1.6724x; 1.1609x over previous
//
#include <hip/hip_runtime.h>
#include <hip/hip_bf16.h>

// CirculantElmanCell: T=1024, B=16, D=2048
// out0: output [T,B,D] f32 ; out1: h [T+1,B,D] f32 (concatenated in d_out)

typedef __attribute__((ext_vector_type(8))) unsigned short us8;
typedef __attribute__((ext_vector_type(8))) __bf16 bf16x8;
typedef __attribute__((ext_vector_type(4))) float f32x4;
typedef __attribute__((ext_vector_type(2))) float f32x2;

__device__ __forceinline__ int SIGF(int a){ return a ^ (((a >> 8) & 3) << 2) ^ ((a >> 6) & 3); }
__device__ __forceinline__ int rev2i(int v){ return ((v & 1) << 1) | ((v >> 1) & 1); }
__device__ __forceinline__ int PERMF(int i){
  return rev2i((i >> 8) & 3) | (rev2i((i >> 6) & 3) << 2) | (rev2i((i >> 4) & 3) << 4)
       | (rev2i((i >> 2) & 3) << 6) | (rev2i(i & 3) << 8);
}

// LDS-only barrier: no vmcnt drain (global loads/stores stay in flight)
#define LDSBAR() do { \
  asm volatile("s_waitcnt lgkmcnt(0)\n\ts_barrier" ::: "memory"); \
  __builtin_amdgcn_sched_barrier(0); \
} while (0)

__device__ __forceinline__ unsigned short f2bf(float f){
  unsigned int u = __float_as_uint(f);
  return (unsigned short)((u + 0x7FFFu + ((u >> 16) & 1u)) >> 16);
}

__device__ __forceinline__ void sincos2pi(float fr, float& sn, float& co){
#if __has_builtin(__builtin_amdgcn_sinf) && __has_builtin(__builtin_amdgcn_cosf)
  sn = __builtin_amdgcn_sinf(fr);   // v_sin_f32: revolutions
  co = __builtin_amdgcn_cosf(fr);
#else
  __sincosf(fr * 6.28318530717958647692f, &sn, &co);
#endif
}

__device__ __forceinline__ float2 cmul(float2 a, float2 b){
  return make_float2(a.x*b.x - a.y*b.y, a.x*b.y + a.y*b.x);
}
__device__ __forceinline__ float2 cmulc(float2 a, float2 b){   // a * conj(b)
  return make_float2(a.x*b.x + a.y*b.y, a.y*b.x - a.x*b.y);
}
__device__ __forceinline__ float2 cadd(float2 a, float2 b){ return make_float2(a.x+b.x, a.y+b.y); }
__device__ __forceinline__ float2 csub(float2 a, float2 b){ return make_float2(a.x-b.x, a.y-b.y); }

__device__ __forceinline__ float tanh_fast(float x){
  float e = __expf(2.0f * x);
  return 1.0f - 2.0f / (e + 1.0f);
}

__device__ __forceinline__ float2 wn(int num, float dinv, int sgn){
  float sn, co; sincos2pi((float)num * dinv, sn, co);
  return make_float2(co, sgn > 0 ? sn : -sn);
}

// ---------------- packed-f32 complex primitives (VOP3P, verified R13) ----------------
__device__ __forceinline__ f32x2 tov(float2 a){ f32x2 r; r[0] = a.x; r[1] = a.y; return r; }
__device__ __forceinline__ float2 tof(f32x2 a){ return make_float2(a[0], a[1]); }

__device__ __forceinline__ float2 pk_fma2(float2 a, float2 b, float2 c){
  f32x2 A = tov(a), B = tov(b), C = tov(c), D;
  asm("v_pk_fma_f32 %0, %1, %2, %3" : "=v"(D) : "v"(A), "v"(B), "v"(C));
  return tof(D);
}
__device__ __forceinline__ float2 pk_cmul(float2 C, float2 z){
  f32x2 Cv = tov(C), Zv = tov(z), D;
  asm("v_pk_mul_f32 %0, %1, %2 op_sel:[0,0] op_sel_hi:[1,0]\n\t"
      "v_pk_fma_f32 %0, %1, %2, %0 op_sel:[1,1,0] op_sel_hi:[0,1,1] neg_lo:[1,0,0]"
      : "=&v"(D) : "v"(Cv), "v"(Zv));
  return tof(D);
}
__device__ __forceinline__ void pk_cfma(float2& acc, float2 C, float2 z){
  f32x2 A = tov(acc), Cv = tov(C), Zv = tov(z);
  asm("v_pk_fma_f32 %0, %1, %2, %0 op_sel:[0,0,0] op_sel_hi:[1,0,1]\n\t"
      "v_pk_fma_f32 %0, %1, %2, %0 op_sel:[1,1,0] op_sel_hi:[0,1,1] neg_lo:[1,0,0]"
      : "+v"(A) : "v"(Cv), "v"(Zv));
  acc = tof(A);
}
__device__ __forceinline__ float2 pk_cmulc(float2 V, float2 m){
  f32x2 Vv = tov(V), Mv = tov(m), D;
  asm("v_pk_mul_f32 %0, %1, %2 op_sel:[0,0] op_sel_hi:[1,0]\n\t"
      "v_pk_fma_f32 %0, %1, %2, %0 op_sel:[1,1,0] op_sel_hi:[0,1,1] neg_hi:[1,0,0]"
      : "=&v"(D) : "v"(Vv), "v"(Mv));
  return tof(D);
}
__device__ __forceinline__ void pk_cfmac(float2& acc, float2 V, float2 m){
  f32x2 A = tov(acc), Vv = tov(V), Mv = tov(m);
  asm("v_pk_fma_f32 %0, %1, %2, %0 op_sel:[0,0,0] op_sel_hi:[1,0,1]\n\t"
      "v_pk_fma_f32 %0, %1, %2, %0 op_sel:[1,1,0] op_sel_hi:[0,1,1] neg_hi:[1,0,0]"
      : "+v"(A) : "v"(Vv), "v"(Mv));
  acc = tof(A);
}

// ---------------- cross-lane exchange primitives ----------------
template<int CTRL>
__device__ __forceinline__ float2 dpp2(float2 v){
  float2 r;
  r.x = __int_as_float(__builtin_amdgcn_mov_dpp(__float_as_int(v.x), CTRL, 0xF, 0xF, true));
  r.y = __int_as_float(__builtin_amdgcn_mov_dpp(__float_as_int(v.y), CTRL, 0xF, 0xF, true));
  return r;
}
template<int IMM>
__device__ __forceinline__ float2 swz2(float2 v){
  float2 r;
  r.x = __int_as_float(__builtin_amdgcn_ds_swizzle(__float_as_int(v.x), IMM));
  r.y = __int_as_float(__builtin_amdgcn_ds_swizzle(__float_as_int(v.y), IMM));
  return r;
}
__device__ __forceinline__ float2 bperm2(int addr, float2 v){
  float2 r;
  r.x = __int_as_float(__builtin_amdgcn_ds_bpermute(addr, __float_as_int(v.x)));
  r.y = __int_as_float(__builtin_amdgcn_ds_bpermute(addr, __float_as_int(v.y)));
  return r;
}
#define DPP_XOR1 0xB1  // quad_perm [1,0,3,2]
#define DPP_XOR2 0x4E  // quad_perm [2,3,0,1]

// ---------------- folded butterfly core: packed (verified R13) ----------------
template<int CONJ>
__device__ __forceinline__ float2 fold2(float2 u, float2 v, float2 C1, float2 C2){
  if (!CONJ){
    float2 d = pk_cmul(C1, u);
    pk_cfma(d, C2, v);
    return d;
  } else {
    float2 d = pk_cmulc(u, C1);
    pk_cfmac(d, v, C2);
    return d;
  }
}

template<int POS>
__device__ __forceinline__ float2 lds4f(const float2* buf, int a0, int a1, int a2, int a3,
                                        float2 sBv, float2 C1, float2 C2){
  float2 in0 = buf[a0], in1 = buf[a1], in2 = buf[a2], in3 = buf[a3];
  float2 u = pk_fma2(in2, sBv, in0);
  float2 v = pk_fma2(in3, sBv, in1);
  return fold2<POS>(u, v, C1, C2);
}

template<int POS>
__device__ __forceinline__ float2 lanes3f(float2 T, int bpa,
    float2 sH2v, float2 E1, float2 E2,
    float2 sH3v, float2 F1, float2 F2,
    float2 sH4v, float2 G1, float2 G2){
  { float2 par = bperm2(bpa, T);
    T = pk_fma2(T, sH2v, par);
    float2 p2 = swz2<0x401F>(T);
    T = fold2<POS>(T, p2, E1, E2); }
  { float2 par = swz2<0x201F>(T);
    T = pk_fma2(T, sH3v, par);
    float2 p2 = swz2<0x101F>(T);
    T = fold2<POS>(T, p2, F1, F2); }
  { float2 par = dpp2<DPP_XOR2>(T);
    T = pk_fma2(T, sH4v, par);
    float2 p2 = dpp2<DPP_XOR1>(T);
    T = fold2<POS>(T, p2, G1, G2); }
  return T;
}

// ---------------- per-thread constants ----------------
struct TW {
  float2 A1, A2, B1, B2;
  float2 E1, E2, F1, F2, G1, G2;
  float2 wmd;
  float2 sB0v, sB1v, sH2v, sH3v, sH4v;
  float sB0;
  int sfi, swP, smir, bpa;
  int aA0, aA1, aA2, aA3, aB0, aB1, aB2, aB3;
  int aM0, aM1, aM2, aM3;
};

__device__ __forceinline__ float2 scal(float2 a, float s){ return make_float2(a.x*s, a.y*s); }

__device__ __forceinline__ void make_tw(int i, TW& S){
  const int p0 = rev2i((i >> 8) & 3);
  const int p1 = rev2i((i >> 6) & 3);
  const int p2v = rev2i((i >> 4) & 3);
  const int p3v = rev2i((i >> 2) & 3);
  const float2 tw0 = wn(((i & 255) * p0) & 1023, 1.0f/1024.0f, -1);
  const float2 tw1 = wn(((i & 63) * p1) & 255, 1.0f/256.0f, -1);
  const float2 tw2 = wn(((i & 15) * p2v) & 63, 1.0f/64.0f, -1);
  const float2 tw3 = wn(((i & 3) * p3v) & 15, 1.0f/16.0f, -1);
  S.wmd = wn(i & 2047, 1.0f/2048.0f, -1);
  const float sD0 = (p0 & 2) ? -1.f : 1.f;  const bool sel0 = p0 & 1;
  const float sD1 = (p1 & 2) ? -1.f : 1.f;  const bool sel1 = p1 & 1;
  const float sB0 = (p0 & 1) ? -1.f : 1.f;
  const float sB1 = (p1 & 1) ? -1.f : 1.f;
  S.sB0 = sB0;
  S.sB0v = make_float2(sB0, sB0);
  S.sB1v = make_float2(sB1, sB1);
  const float2 rho0 = sel0 ? make_float2(0.f,-1.f) : make_float2(1.f,0.f);
  const float2 rho1 = sel1 ? make_float2(0.f,-1.f) : make_float2(1.f,0.f);
  S.A1 = tw0; S.A2 = scal(cmul(tw0, rho0), sD0);
  S.B1 = tw1; S.B2 = scal(cmul(tw1, rho1), sD1);
  const bool c02 = (i >> 4) & 1, c12 = (i >> 5) & 1;
  const bool c03 = (i >> 2) & 1, c13 = (i >> 3) & 1;
  const bool c04 = i & 1,        c14 = (i >> 1) & 1;
  const float sH2 = c12 ? -1.f : 1.f;
  const float sH3 = c13 ? -1.f : 1.f;
  const float sH4 = c14 ? -1.f : 1.f;
  S.sH2v = make_float2(sH2, sH2);
  S.sH3v = make_float2(sH3, sH3);
  S.sH4v = make_float2(sH4, sH4);
  {
    const float sL = c02 ? -1.f : 1.f;
    const float2 rho = c12 ? make_float2(0.f,-1.f) : make_float2(1.f,0.f);
    const float2 al = c02 ? scal(rho, sL) : make_float2(1.f,0.f);
    const float2 be = c02 ? make_float2(1.f,0.f) : scal(rho, sL);
    S.E1 = cmul(tw2, al); S.E2 = cmul(tw2, be);
  }
  {
    const float sL = c03 ? -1.f : 1.f;
    const float2 rho = c13 ? make_float2(0.f,-1.f) : make_float2(1.f,0.f);
    const float2 al = c03 ? scal(rho, sL) : make_float2(1.f,0.f);
    const float2 be = c03 ? make_float2(1.f,0.f) : scal(rho, sL);
    S.F1 = cmul(tw3, al); S.F2 = cmul(tw3, be);
  }
  {
    const float sL = c04 ? -1.f : 1.f;
    const float2 rho = c14 ? make_float2(0.f,-1.f) : make_float2(1.f,0.f);
    S.G1 = c04 ? scal(rho, sL) : make_float2(1.f,0.f);
    S.G2 = c04 ? make_float2(1.f,0.f) : scal(rho, sL);
  }
  S.sfi = SIGF(i); S.swP = SIGF(PERMF(i)); S.smir = SIGF((1024 - i) & 1023);
  S.bpa = ((i & 63) ^ 32) << 2;
  const int r256 = i & 255;
  S.aA0 = SIGF(r256); S.aA1 = SIGF(r256 + 256); S.aA2 = SIGF(r256 + 512); S.aA3 = SIGF(r256 + 768);
  const int b64 = (i & ~255) + (i & 63);
  S.aB0 = SIGF(b64); S.aB1 = SIGF(b64 + 64); S.aB2 = SIGF(b64 + 128); S.aB3 = SIGF(b64 + 192);
  S.aM0 = SIGF((1024 - r256) & 1023);
  S.aM1 = SIGF((1024 - (r256 + 256)) & 1023);
  S.aM2 = SIGF((1024 - (r256 + 512)) & 1023);
  S.aM3 = SIGF((1024 - (r256 + 768)) & 1023);
}

// 5-phase conv body (R13-verified). Result at bB[S.sfi]; caller reads, then barriers.
__device__ __forceinline__ void fftconv5(float2* hz, float2* bA, float2* bB,
                                         const TW& S, const float2* U, const float2* V){
  float2 T = lds4f<0>(hz, S.aA0, S.aA1, S.aA2, S.aA3, S.sB0v, S.A1, S.A2);
  bA[S.sfi] = T; LDSBAR();
  T = lds4f<0>(bA, S.aB0, S.aB1, S.aB2, S.aB3, S.sB1v, S.B1, S.B2);
  T = lanes3f<0>(T, S.bpa, S.sH2v, S.E1, S.E2, S.sH3v, S.F1, S.F2, S.sH4v, S.G1, S.G2);
  bB[S.swP] = T; LDSBAR();
  {
    float2 z0 = bB[S.aA0], z1 = bB[S.aA1], z2 = bB[S.aA2], z3 = bB[S.aA3];
    float2 m0 = bB[S.aM0], m1 = bB[S.aM1], m2 = bB[S.aM2], m3 = bB[S.aM3];
    float2 y = pk_cmul(U[0], z0);
    pk_cfma(y, U[1], z1);
    pk_cfma(y, U[2], z2);
    pk_cfma(y, U[3], z3);
    pk_cfmac(y, V[0], m0);
    pk_cfmac(y, V[1], m1);
    pk_cfmac(y, V[2], m2);
    pk_cfmac(y, V[3], m3);
    bA[S.sfi] = y;
  }
  LDSBAR();
  T = lds4f<1>(bA, S.aB0, S.aB1, S.aB2, S.aB3, S.sB1v, S.B1, S.B2);
  T = lanes3f<1>(T, S.bpa, S.sH2v, S.E1, S.E2, S.sH3v, S.F1, S.F2, S.sH4v, S.G1, S.G2);
  bB[S.swP] = T; LDSBAR();
}

// in-block lam + P/Q from real 2048-seq c (verified R9-R13)
__device__ __forceinline__ void make_PQ(const float* __restrict__ c, int i, const TW& S,
                                        float2* hz, float2* bA, float2* bB,
                                        float2& P, float2& Q){
  hz[S.sfi] = ((const float2*)c)[i];
  __syncthreads();
  float2 T = lds4f<0>(hz, S.aA0, S.aA1, S.aA2, S.aA3, S.sB0v, S.A1, S.A2);
  bA[S.sfi] = T;
  __syncthreads();
  T = lds4f<0>(bA, S.aB0, S.aB1, S.aB2, S.aB3, S.sB1v, S.B1, S.B2);
  T = lanes3f<0>(T, S.bpa, S.sH2v, S.E1, S.E2, S.sH3v, S.F1, S.F2, S.sH4v, S.G1, S.G2);
  bB[S.swP] = T;
  __syncthreads();
  float2 zk = bB[S.sfi], zp = bB[S.smir];
  float2 E = make_float2(0.5f*(zk.x+zp.x),  0.5f*(zk.y-zp.y));
  float2 O = make_float2(0.5f*(zk.y+zp.y), -0.5f*(zk.x-zp.x));
  float2 w = S.wmd;
  float2 wO = cmul(w, O);
  float2 lamA = scal(cadd(E, wO), 1.0f/2048.0f);
  float2 lamB = scal(csub(E, wO), 1.0f/2048.0f);
  float2 al = make_float2(0.5f*(1.0f + w.y), -0.5f*w.x);
  float2 be = make_float2(0.5f*(1.0f - w.y),  0.5f*w.x);
  float2 ga = make_float2(1.0f + w.y,  w.x);
  float2 de = make_float2(1.0f - w.y, -w.x);
  float2 gA = cmul(ga, lamA), dB = cmul(de, lamB);
  P = cadd(cmul(gA, al), cmul(dB, be));
  Q = cadd(cmul(gA, be), cmul(dB, al));
  __syncthreads();
}

// stage P,Q through LDS and gather per-thread U/V for the fused phase
__device__ __forceinline__ void make_UV(int i, const TW& S, float2 P, float2 Q,
                                        float2* bA, float2* bB, float2* U, float2* V){
  ((float2*)bB)[i] = P;
  ((float2*)bA)[i] = Q;
  __syncthreads();
  const int r256 = i & 255;
  const float2 cA1 = make_float2(S.A1.x, -S.A1.y);
  const float2 cA2 = make_float2(S.A2.x, -S.A2.y);
  float2 cc[4];
  cc[0] = cA1; cc[1] = cA2; cc[2] = scal(cA1, S.sB0); cc[3] = scal(cA2, S.sB0);
  #pragma unroll
  for (int q = 0; q < 4; ++q){
    const int n = r256 + 256 * q;
    U[q] = cmul(cc[q], ((float2*)bB)[n]);
    V[q] = cmul(cc[q], ((float2*)bA)[n]);
  }
  __syncthreads();
}

// ---------------- f32 -> bf16 bulk convert (R8-proven) ----------------
__global__ __launch_bounds__(256) void cvt_bf16(const float* __restrict__ in,
                                                unsigned short* __restrict__ out, int n8){
  int i = blockIdx.x * 256 + threadIdx.x;
  if (i >= n8) return;
  float4 a = ((const float4*)in)[2 * i];
  float4 b = ((const float4*)in)[2 * i + 1];
  us8 r;
  r[0] = f2bf(a.x); r[1] = f2bf(a.y); r[2] = f2bf(a.z); r[3] = f2bf(a.w);
  r[4] = f2bf(b.x); r[5] = f2bf(b.y); r[6] = f2bf(b.z); r[7] = f2bf(b.w);
  ((us8*)out)[i] = r;
}

// =====================================================================
// mega v9 = R13 + flag-poll prefetch + 8B system-scope data accesses.
// blocks [0,16) recur ; [16,144) circx ; [144,1168) gemm (4 tiles each, bf16).
// =====================================================================
__global__ __launch_bounds__(1024, 4) void mega(
    const float* __restrict__ x, const unsigned short* __restrict__ xb,
    const unsigned short* __restrict__ Wb, const float* __restrict__ h0,
    const float* __restrict__ ch, const float* __restrict__ cx,
    const float* __restrict__ bias, const float* __restrict__ bg,
    float* __restrict__ outp, float* __restrict__ houtp, int* __restrict__ flags){
  __shared__ __align__(16) char smem[98304];   // 96KB: forces 1 block/CU
  const int bid = blockIdx.x;
  const int tid = threadIdx.x;
  int* gcnt = flags;
  int* wcnt = flags + 128;

  if (bid < 16){
    // ---------------- recur consumer (dedicated CU) ----------------
    float2* hz = (float2*)smem; float2* bA = hz + 1024; float2* bB = hz + 2048;
    const int i = tid, b = bid;
    TW S; make_tw(i, S);
    float2 P, Q; make_PQ(ch, i, S, hz, bA, bB, P, Q);
    float2 U[4], V[4]; make_UV(i, S, P, Q, bA, bB, U, V);
    {
      const float2* h02 = (const float2*)(h0 + (size_t)b * 2048);
      float2* hrow0 = (float2*)(houtp + (size_t)b * 2048);
      float2 v = h02[i]; hz[S.sfi] = v; hrow0[i] = v;
    }
    __syncthreads();
    int pg = 0, pw = 0;   // prefetched flag values (tid0 only)
    #pragma unroll 1
    for (int t = 0; t < 1024; ++t){
      if ((t & 7) == 0){
        if (tid == 0){
          const int xk = t >> 3;
          while (pg < 32){
            pg = __hip_atomic_load(&gcnt[xk], __ATOMIC_RELAXED, __HIP_MEMORY_SCOPE_SYSTEM);
            if (pg < 32) __builtin_amdgcn_s_sleep(16);
          }
          while (pw < 128){
            pw = __hip_atomic_load(&wcnt[xk], __ATOMIC_RELAXED, __HIP_MEMORY_SCOPE_SYSTEM);
            if (pw < 128) __builtin_amdgcn_s_sleep(16);
          }
          if (xk < 127){   // prefetch next chunk; latency hides across 8 steps
            pg = __hip_atomic_load(&gcnt[xk + 1], __ATOMIC_RELAXED, __HIP_MEMORY_SCOPE_SYSTEM);
            pw = __hip_atomic_load(&wcnt[xk + 1], __ATOMIC_RELAXED, __HIP_MEMORY_SCOPE_SYSTEM);
          }
        }
        __syncthreads();
      }
      float* orow = outp  + ((size_t)t * 16 + b) * 2048;
      float* hrow = houtp + ((size_t)(t + 1) * 16 + b) * 2048;
      // single 8B system-scope (L2-bypass) loads
      unsigned long long pv = __hip_atomic_load((const unsigned long long*)(orow + 2*i),
                                                __ATOMIC_RELAXED, __HIP_MEMORY_SCOPE_SYSTEM);
      unsigned long long gvv = __hip_atomic_load((const unsigned long long*)(hrow + 2*i),
                                                 __ATOMIC_RELAXED, __HIP_MEMORY_SCOPE_SYSTEM);
      float2 pr = __builtin_bit_cast(float2, pv);
      float2 gv = __builtin_bit_cast(float2, gvv);
      fftconv5(hz, bA, bB, S, U, V);
      float2 y = bB[S.sfi];
      float hx = tanh_fast(y.x + pr.x);
      float hy = tanh_fast(y.y + pr.y);
      float ox = hx * gv.x, oy = hy * gv.y;
      asm volatile("" : "+v"(hx), "+v"(hy) : "v"(gv.x), "v"(gv.y));
      float2 hv = make_float2(hx, hy);
      hz[S.sfi] = hv;
      *(float2*)(hrow + 2 * i) = hv;
      *(float2*)(orow + 2 * i) = make_float2(ox, oy);
      LDSBAR();
    }
  } else if (bid < 144){
    // ---------------- circx producer: rows cblk + 128*k ----------------
    float2* hz = (float2*)smem; float2* bA = hz + 1024; float2* bB = hz + 2048;
    const int i = tid, cblk = bid - 16;
    TW S; make_tw(i, S);
    float2 P, Q; make_PQ(cx, i, S, hz, bA, bB, P, Q);
    float2 U[4], V[4]; make_UV(i, S, P, Q, bA, bB, U, V);
    const float2 bv = ((const float2*)bias)[i];
    #pragma unroll 1
    for (int k = 0; k < 128; ++k){
      const size_t row = (size_t)cblk + ((size_t)k << 7);
      hz[S.sfi] = ((const float2*)(x + row * 2048))[i];
      LDSBAR();
      fftconv5(hz, bA, bB, S, U, V);
      float2 y = bB[S.sfi];
      float* pd = outp + row * 2048 + 2 * i;
      float2 yv = make_float2(y.x + bv.x, y.y + bv.y);
      __hip_atomic_store((unsigned long long*)pd, __builtin_bit_cast(unsigned long long, yv),
                         __ATOMIC_RELAXED, __HIP_MEMORY_SCOPE_SYSTEM);
      __syncthreads();   // vmcnt(0) drain: stores complete at L3 before flag
      if (tid == 0)
        __hip_atomic_fetch_add(&wcnt[k], 1, __ATOMIC_RELAXED, __HIP_MEMORY_SCOPE_SYSTEM);
    }
  } else {
    // ---------------- gemm producer: 4 tiles 128x64, bf16, LDA=40 pad (R8-proven) ----------------
    const int q = bid - 144;
    const int g = tid >> 8, tid8 = tid & 255;
    const int tau = q * 4 + g;
    const int m0 = (tau >> 5) * 128, n0 = (tau & 31) * 64;
    unsigned short* As = (unsigned short*)(smem + g * 15360);   // 128 x 40 (padded)
    unsigned short* Bs = As + 5120;                             // 64 x 40
    const int lane = tid8 & 63, wave = tid8 >> 6;
    const int srA = tid8 >> 1, scA = (tid8 & 1) << 4;
    const int srB = tid8 >> 2, scB = (tid8 & 3) << 3;
    const unsigned short* ga = xb + (size_t)(m0 + srA) * 2048 + scA;
    const unsigned short* gb = Wb + (size_t)(n0 + srB) * 2048 + scB;
    unsigned short* la = As + srA * 40 + scA;
    unsigned short* lb = Bs + srB * 40 + scB;
    f32x4 acc[2][4];
    #pragma unroll
    for (int m = 0; m < 2; ++m)
      #pragma unroll
      for (int n = 0; n < 4; ++n)
        acc[m][n] = f32x4{0.f, 0.f, 0.f, 0.f};
    const int arow = wave * 32 + (lane & 15);
    const int brow = lane & 15;
    const int koff = (lane >> 4) * 8;
    for (int ks = 0; ks < 64; ++ks){
      const int k0 = ks * 32;
      us8 va0 = *(const us8*)(ga + k0);
      us8 va1 = *(const us8*)(ga + k0 + 8);
      us8 vb0 = *(const us8*)(gb + k0);
      __syncthreads();
      *(us8*)(la)     = va0; *(us8*)(la + 8) = va1;
      *(us8*)(lb)     = vb0;
      __syncthreads();
      bf16x8 av[2], bvv[4];
      #pragma unroll
      for (int m = 0; m < 2; ++m) av[m] = *(const bf16x8*)(As + (arow + m * 16) * 40 + koff);
      #pragma unroll
      for (int n = 0; n < 4; ++n) bvv[n] = *(const bf16x8*)(Bs + (brow + n * 16) * 40 + koff);
      #pragma unroll
      for (int m = 0; m < 2; ++m)
        #pragma unroll
        for (int n = 0; n < 4; ++n)
          acc[m][n] = __builtin_amdgcn_mfma_f32_16x16x32_bf16(av[m], bvv[n], acc[m][n], 0, 0, 0);
    }
    #pragma unroll
    for (int n = 0; n < 4; ++n){
      const int ng = n0 + n * 16 + (lane & 15);
      const float bgv = bg[ng];
      #pragma unroll
      for (int m = 0; m < 2; ++m){
        const int mbase = m0 + wave * 32 + m * 16 + (lane >> 4) * 4;
        #pragma unroll
        for (int r = 0; r < 4; ++r){
          float v = acc[m][n][r] + bgv;
          float s = v / (1.0f + __expf(-v));
          __hip_atomic_store(&houtp[(size_t)(mbase + r + 16) * 2048 + ng], s,
                             __ATOMIC_RELAXED, __HIP_MEMORY_SCOPE_SYSTEM);
        }
      }
    }
    __syncthreads();   // vmcnt(0) drain before flag
    if (tid == 0)
      __hip_atomic_fetch_add(&gcnt[q >> 3], 4, __ATOMIC_RELAXED, __HIP_MEMORY_SCOPE_SYSTEM);
  }
}

extern "C" void kernel_launch(void* const* d_in, const int* in_sizes, int n_in,
                              void* d_out, int out_size, void* d_ws, size_t ws_size,
                              hipStream_t stream){
  const float* x  = (const float*)d_in[0];
  const float* h0 = (const float*)d_in[1];
  const float* ch = (const float*)d_in[2];
  const float* cx = (const float*)d_in[3];
  const float* Wg = (const float*)d_in[4];
  const float* bb = (const float*)d_in[5];
  const float* bg = (const float*)d_in[6];
  float* outp  = (float*)d_out;                        // [T,B,D]
  float* houtp = outp + (size_t)1024 * 16 * 2048;      // [T+1,B,D]

  char* w = (char*)d_ws;
  unsigned short* xb = (unsigned short*)w; w += (size_t)16384 * 2048 * 2;
  unsigned short* Wb = (unsigned short*)w; w += (size_t)2048 * 2048 * 2;
  int* flags = (int*)w; w += 256 * sizeof(int);

  cvt_bf16<<<dim3(16384), dim3(256), 0, stream>>>(x,  xb, 16384 * 2048 / 8);
  cvt_bf16<<<dim3(2048),  dim3(256), 0, stream>>>(Wg, Wb,  2048 * 2048 / 8);
  hipMemsetAsync(flags, 0, 256 * sizeof(int), stream);
  mega<<<dim3(1168), dim3(1024), 0, stream>>>(x, xb, Wb, h0, ch, cx, bb, bg,
                                              outp, houtp, flags);
}